// Round 3
// baseline (652.213 us; speedup 1.0000x reference)
//
#include <hip/hip_runtime.h>

// ---------------------------------------------------------------------------
// GCN pipeline, bucket-binned (no per-node CSR):
//   deg histogram -> dinv + per-bucket counts (64 nodes/bucket) -> bucket scan
//   -> bin edges (packed (src<<6)|localdst, 4B) -> transform1 (dinv*x@W1)
//   -> bucket_aggregate<64> (wave-per-bucket, LDS acc) -> transform2
//   -> bucket_aggregate<32> -> fc head
// Rationale: round-2 place_edges showed 105MB WRITE_SIZE for 6.4MB payload
// (17x amplification from fully-random 4B scatter). Binning to 1563 regions
// keeps write lines hot; LDS-accumulated aggregation removes the per-node
// CSR and the 64x-redundant src-index loads.
// ---------------------------------------------------------------------------

__global__ void count_deg(const int* __restrict__ dst, int* __restrict__ deg, int E) {
    int e = blockIdx.x * blockDim.x + threadIdx.x;
    if (e < E) atomicAdd(&deg[dst[e]], 1);
}

// wave per bucket: dinv[node] and bcnt[b] = sum of deg over the bucket's 64 nodes
__global__ void dinv_bcnt(const int* __restrict__ deg, float* __restrict__ dinv,
                          int* __restrict__ bcnt, int n, int NB) {
    int b = blockIdx.x * 4 + (threadIdx.x >> 6);
    int lane = threadIdx.x & 63;
    if (b >= NB) return;
    int node = (b << 6) + lane;
    int d = (node < n) ? deg[node] : 0;
    if (node < n) dinv[node] = 1.0f / sqrtf((float)(d + 1));  // +1 self loop
    int s = d;
#pragma unroll
    for (int o = 32; o > 0; o >>= 1) s += __shfl_down(s, o, 64);
    if (lane == 0) bcnt[b] = s;
}

// single-block exclusive scan of bucket counts (NB <= 2048)
__global__ void scan_buckets(const int* __restrict__ bcnt, int* __restrict__ boffs,
                             int* __restrict__ bcursor, int NB) {
    __shared__ int lds[256];
    int t = threadIdx.x;
    int v[8];
    int sum = 0;
#pragma unroll
    for (int j = 0; j < 8; ++j) {
        int i = t * 8 + j;
        v[j] = (i < NB) ? bcnt[i] : 0;
        sum += v[j];
    }
    lds[t] = sum;
    __syncthreads();
    int incl = sum;
    for (int d = 1; d < 256; d <<= 1) {
        int add = (t >= d) ? lds[t - d] : 0;
        __syncthreads();
        incl += add;
        lds[t] = incl;
        __syncthreads();
    }
    int run = incl - sum;
#pragma unroll
    for (int j = 0; j < 8; ++j) {
        int i = t * 8 + j;
        if (i < NB) { boffs[i] = run; bcursor[i] = run; }
        run += v[j];
    }
    if (t == 255) boffs[NB] = incl;  // grand total = E
}

// scatter edges into bucket regions; payload packed to 4B: (src<<6)|(dst&63)
__global__ void bin_edges(const int* __restrict__ src, const int* __restrict__ dst,
                          int* __restrict__ bcursor, unsigned* __restrict__ binned, int E) {
    int e = blockIdx.x * blockDim.x + threadIdx.x;
    if (e < E) {
        int d = dst[e];
        int p = atomicAdd(&bcursor[d >> 6], 1);
        binned[p] = ((unsigned)src[e] << 6) | (unsigned)(d & 63);
    }
}

// h1'[i,f] = dinv[i] * sum_k x[i,k]*W1[k,f]   (x: [n,5], W1: [5,64])
__global__ void transform1(const float* __restrict__ x, const float* __restrict__ W1,
                           const float* __restrict__ dinv, float* __restrict__ h, int n) {
    __shared__ float w[320];
    int t = threadIdx.x;
    w[t] = W1[t];
    if (t < 64) w[t + 256] = W1[t + 256];
    __syncthreads();
    int idx = blockIdx.x * 256 + t;
    int i = idx >> 6, f = idx & 63;
    if (i < n) {
        float acc = 0.f;
#pragma unroll
        for (int k = 0; k < 5; ++k) acc += x[i * 5 + k] * w[k * 64 + f];
        h[idx] = acc * dinv[i];
    }
}

// wave-per-bucket aggregation with LDS accumulator (64 nodes x F floats/wave).
// out[i,:] = relu(dinv[i]*(h'[i,:] + sum_{e: dst=i} h'[src,:]) + b)
template <int F, int WAVES>
__global__ __launch_bounds__(WAVES * 64) void bucket_aggregate(
    const float* __restrict__ h, const unsigned* __restrict__ binned,
    const int* __restrict__ boffs, const float* __restrict__ dinv,
    const float* __restrict__ bias, float* __restrict__ out, int n, int NB) {
    __shared__ float acc[WAVES * 64 * F];
    int wave = threadIdx.x >> 6;
    int lane = threadIdx.x & 63;
    int b = blockIdx.x * WAVES + wave;
    if (b >= NB) return;  // no barriers below; waves are independent
    int node0 = b << 6;
    int nn = min(64, n - node0);
    float* A = acc + wave * (64 * F);

    // init with self-loop term h'[node]
    for (int idx = lane; idx < nn * F; idx += 64) A[idx] = h[(size_t)node0 * F + idx];

    int e0 = boffs[b], e1 = boffs[b + 1];
    for (int base = e0; base < e1; base += 64) {
        int m = min(64, e1 - base);
        unsigned w = (base + lane < e1) ? binned[base + lane] : 0u;

        if constexpr (F == 64) {
            int k = 0;
            for (; k + 8 <= m; k += 8) {
                float v[8];
                int jd[8];
#pragma unroll
                for (int u = 0; u < 8; ++u) {
                    unsigned wk = __shfl(w, k + u, 64);
                    jd[u] = (int)(wk & 63u);
                    v[u] = h[(size_t)(wk >> 6) * 64 + lane];
                }
#pragma unroll
                for (int u = 0; u < 8; ++u) A[jd[u] * 64 + lane] += v[u];
            }
            for (; k < m; ++k) {
                unsigned wk = __shfl(w, k, 64);
                A[(int)(wk & 63u) * 64 + lane] += h[(size_t)(wk >> 6) * 64 + lane];
            }
        } else {  // F == 32: two edges per substep (lane halves)
            int half = lane >> 5, f = lane & 31;
            int k = 0;
            for (; k + 8 <= m; k += 8) {
                float v[4];
                unsigned wa[4], wb[4];
#pragma unroll
                for (int u = 0; u < 4; ++u) {
                    wa[u] = __shfl(w, k + 2 * u, 64);
                    wb[u] = __shfl(w, k + 2 * u + 1, 64);
                    unsigned wk = half ? wb[u] : wa[u];
                    v[u] = h[(size_t)(wk >> 6) * 32 + f];
                }
#pragma unroll
                for (int u = 0; u < 4; ++u) {
                    unsigned wk = half ? wb[u] : wa[u];
                    int jd = (int)(wk & 63u);
                    if ((wa[u] & 63u) == (wb[u] & 63u)) {
                        // same dst node in both halves: combine, lower half writes
                        float o = __shfl(v[u], lane ^ 32, 64);
                        if (!half) A[jd * 32 + f] += v[u] + o;
                    } else {
                        A[jd * 32 + f] += v[u];
                    }
                }
            }
            for (; k + 2 <= m; k += 2) {
                unsigned w0 = __shfl(w, k, 64), w1 = __shfl(w, k + 1, 64);
                unsigned wk = half ? w1 : w0;
                int jd = (int)(wk & 63u);
                float v = h[(size_t)(wk >> 6) * 32 + f];
                if ((w0 & 63u) == (w1 & 63u)) {
                    float o = __shfl(v, lane ^ 32, 64);
                    if (!half) A[jd * 32 + f] += v + o;
                } else {
                    A[jd * 32 + f] += v;
                }
            }
            if (k < m) {  // odd leftover: lower half only
                unsigned wk = __shfl(w, k, 64);
                if (!half) A[(int)(wk & 63u) * 32 + f] += h[(size_t)(wk >> 6) * 32 + f];
            }
        }
    }

    // epilogue: scale, bias, relu, coalesced store
    for (int idx = lane; idx < nn * F; idx += 64) {
        int j = idx / F, f = idx & (F - 1);
        float v = dinv[node0 + j] * A[idx] + bias[f];
        out[(size_t)node0 * F + idx] = fmaxf(v, 0.0f);
    }
}

// h2'[i,g] = dinv[i] * sum_k x1[i,k]*W2[k,g]   (x1: [n,64], W2: [64,32])
__global__ void transform2(const float* __restrict__ x1, const float* __restrict__ W2,
                           const float* __restrict__ dinv, float* __restrict__ h2, int n) {
    __shared__ float ws[64 * 32];
    __shared__ float xs[8 * 64];
    int t = threadIdx.x;
#pragma unroll
    for (int k = 0; k < 8; ++k) ws[t + k * 256] = W2[t + k * 256];
    int blockNode = blockIdx.x * 8;
    int g0 = blockNode * 64;
    if (g0 + t < n * 64) xs[t] = x1[g0 + t];
    if (g0 + 256 + t < n * 64) xs[t + 256] = x1[g0 + 256 + t];
    __syncthreads();
    int li = t >> 5, g = t & 31;
    int i = blockNode + li;
    if (i >= n) return;
    float acc = 0.f;
#pragma unroll
    for (int k = 0; k < 64; ++k) acc += xs[li * 64 + k] * ws[k * 32 + g];
    h2[(size_t)i * 32 + g] = acc * dinv[i];
}

// x3 = relu(x2@fcW1 + fcb1); out = x3@fcW2 + fcb2   (per-node thread)
__global__ void fc_head(const float* __restrict__ x2, const float* __restrict__ fcW1,
                        const float* __restrict__ fcb1, const float* __restrict__ fcW2,
                        const float* __restrict__ fcb2, float* __restrict__ out, int n) {
    __shared__ float w1s[512];
    __shared__ float w2s[32];
    __shared__ float b1s[16];
    __shared__ float b2s[2];
    int t = threadIdx.x;
    w1s[t] = fcW1[t];
    w1s[t + 256] = fcW1[t + 256];
    if (t < 32) w2s[t] = fcW2[t];
    if (t < 16) b1s[t] = fcb1[t];
    if (t < 2) b2s[t] = fcb2[t];
    __syncthreads();
    int i = blockIdx.x * 256 + t;
    if (i >= n) return;
    float r[32];
    const float4* xv = (const float4*)(x2 + (size_t)i * 32);
#pragma unroll
    for (int q = 0; q < 8; ++q) {
        float4 v = xv[q];
        r[4 * q + 0] = v.x; r[4 * q + 1] = v.y;
        r[4 * q + 2] = v.z; r[4 * q + 3] = v.w;
    }
    float x3[16];
#pragma unroll
    for (int j = 0; j < 16; ++j) {
        float a = b1s[j];
#pragma unroll
        for (int k = 0; k < 32; ++k) a += r[k] * w1s[k * 16 + j];
        x3[j] = fmaxf(a, 0.f);
    }
#pragma unroll
    for (int o = 0; o < 2; ++o) {
        float a = b2s[o];
#pragma unroll
        for (int j = 0; j < 16; ++j) a += x3[j] * w2s[j * 2 + o];
        out[(size_t)i * 2 + o] = a;
    }
}

extern "C" void kernel_launch(void* const* d_in, const int* in_sizes, int n_in,
                              void* d_out, int out_size, void* d_ws, size_t ws_size,
                              hipStream_t stream) {
    const float* edge_attr = (const float*)d_in[0];
    const int* edge_index  = (const int*)d_in[1];
    const float* W1   = (const float*)d_in[2];
    const float* b1   = (const float*)d_in[3];
    const float* W2   = (const float*)d_in[4];
    const float* b2   = (const float*)d_in[5];
    const float* fcW1 = (const float*)d_in[6];
    const float* fcb1 = (const float*)d_in[7];
    const float* fcW2 = (const float*)d_in[8];
    const float* fcb2 = (const float*)d_in[9];
    float* out = (float*)d_out;

    int n = in_sizes[0] / 5;
    int E = in_sizes[1] / 2;
    int NB = (n + 63) >> 6;  // 64-node buckets
    const int* src = edge_index;
    const int* dst = edge_index + E;

    char* ws = (char*)d_ws;
    auto alloc = [&](size_t bytes) {
        char* p = ws;
        ws += (bytes + 255) & ~(size_t)255;
        return p;
    };
    int*      deg     = (int*)alloc((size_t)n * 4);
    float*    dinv    = (float*)alloc((size_t)n * 4);
    int*      bcnt    = (int*)alloc((size_t)NB * 4);
    int*      boffs   = (int*)alloc((size_t)(NB + 1) * 4);
    int*      bcursor = (int*)alloc((size_t)NB * 4);
    unsigned* binned  = (unsigned*)alloc((size_t)E * 4);
    float*    bufA    = (float*)alloc((size_t)n * 64 * 4);
    float*    bufB    = (float*)alloc((size_t)n * 64 * 4);

    hipMemsetAsync(deg, 0, (size_t)n * sizeof(int), stream);

    int eb = (E + 255) / 256;
    count_deg<<<eb, 256, 0, stream>>>(dst, deg, E);
    dinv_bcnt<<<(NB + 3) / 4, 256, 0, stream>>>(deg, dinv, bcnt, n, NB);
    scan_buckets<<<1, 256, 0, stream>>>(bcnt, boffs, bcursor, NB);
    bin_edges<<<eb, 256, 0, stream>>>(src, dst, bcursor, binned, E);

    transform1<<<(n * 64 + 255) / 256, 256, 0, stream>>>(edge_attr, W1, dinv, bufA, n);
    bucket_aggregate<64, 2><<<(NB + 1) / 2, 128, 0, stream>>>(bufA, binned, boffs, dinv,
                                                              b1, bufB, n, NB);
    transform2<<<(n + 7) / 8, 256, 0, stream>>>(bufB, W2, dinv, bufA, n);
    bucket_aggregate<32, 4><<<(NB + 3) / 4, 256, 0, stream>>>(bufA, binned, boffs, dinv,
                                                              b2, bufB, n, NB);
    fc_head<<<(n + 255) / 256, 256, 0, stream>>>(bufB, fcW1, fcb1, fcW2, fcb2, out, n);
}

// Round 4
// 387.545 us; speedup vs baseline: 1.6829x; 1.6829x over previous
//
#include <hip/hip_runtime.h>

// ---------------------------------------------------------------------------
// GCN pipeline, round 4:
//   count_deg -> per-node exclusive scan (offs) -> multisplit (tile counting
//   sort into 256-node coarse buckets, coalesced writes, 77K global atomics)
//   -> place_fine (per-bucket LDS cursors -> exact per-node CSR) ->
//   transform1 -> aggregate<64> (round-2 version: broadcast index + coalesced
//   row gather) -> transform2 -> aggregate<32> -> fc head.
// Round-3 lesson: few global cursors = atomic serialization (238us); round-2
// lesson: 100K-region 4B scatter = 17x write amp (130us). Multisplit avoids
// both: atomics once per (tile,bucket), payload writes as coalesced runs.
// ---------------------------------------------------------------------------

#define MS_TILE 8192
#define MAXB 512  // padded coarse-bucket count (NBkt = ceil(n/256) <= 512)

__global__ void count_deg(const int* __restrict__ dst, int* __restrict__ deg, int E) {
    int e = blockIdx.x * blockDim.x + threadIdx.x;
    if (e < E) atomicAdd(&deg[dst[e]], 1);
}

// Exclusive scan, tile = 2048 elems (256 thr x 8 items)
__global__ void scanA(const int* __restrict__ deg, int* __restrict__ offs,
                      int* __restrict__ bsums, int n) {
    __shared__ int lds[256];
    int t = threadIdx.x;
    int base = blockIdx.x * 2048 + t * 8;
    int v[8];
    int sum = 0;
#pragma unroll
    for (int j = 0; j < 8; ++j) {
        int i = base + j;
        v[j] = (i < n) ? deg[i] : 0;
        sum += v[j];
    }
    lds[t] = sum;
    __syncthreads();
    int incl = sum;
    for (int d = 1; d < 256; d <<= 1) {
        int add = (t >= d) ? lds[t - d] : 0;
        __syncthreads();
        incl += add;
        lds[t] = incl;
        __syncthreads();
    }
    int run = incl - sum;
#pragma unroll
    for (int j = 0; j < 8; ++j) {
        int i = base + j;
        if (i < n) offs[i] = run;
        run += v[j];
    }
    if (t == 255) bsums[blockIdx.x] = incl;
}

__global__ void scanB(int* __restrict__ bsums, int nb) {
    int l = threadIdx.x;
    int v = (l < nb) ? bsums[l] : 0;
    int incl = v;
#pragma unroll
    for (int d = 1; d < 64; d <<= 1) {
        int up = __shfl_up(incl, d, 64);
        if (l >= d) incl += up;
    }
    if (l < nb) bsums[l] = incl - v;
}

// finalize offs, dinv, and coarse-bucket global cursors (gcur[b] = offs[256b])
__global__ void scanC(int* __restrict__ offs, const int* __restrict__ bsums,
                      const int* __restrict__ deg, float* __restrict__ dinv,
                      int* __restrict__ gcur, int n) {
    int i = blockIdx.x * blockDim.x + threadIdx.x;
    if (i < n) {
        int off = offs[i] + bsums[i >> 11];
        offs[i] = off;
        dinv[i] = 1.0f / sqrtf((float)(deg[i] + 1));  // +1 self loop
        if ((i & 255) == 0) gcur[i >> 8] = off;
    }
}

// Tile counting-sort into 256-node coarse buckets. Payload: (src<<8)|(dst&255).
__global__ __launch_bounds__(256) void multisplit(
    const int* __restrict__ src, const int* __restrict__ dst,
    int* __restrict__ gcur, unsigned* __restrict__ binned, int E) {
    __shared__ unsigned stage[MS_TILE];
    __shared__ int hist[MAXB];
    __shared__ int hoff[MAXB + 1];
    __shared__ int hcur[MAXB];
    __shared__ int gbase[MAXB];
    __shared__ int scn[256];
    int t = threadIdx.x;
    int base = blockIdx.x * MS_TILE;
    int cnt = min(MS_TILE, E - base);

    hist[2 * t] = 0;
    hist[2 * t + 1] = 0;
    __syncthreads();
    for (int k = t; k < cnt; k += 256)
        atomicAdd(&hist[dst[base + k] >> 8], 1);
    __syncthreads();
    // blocked exclusive scan: thread t owns hist[2t], hist[2t+1]
    int a0 = hist[2 * t], a1 = hist[2 * t + 1];
    int s = a0 + a1;
    scn[t] = s;
    __syncthreads();
    int incl = s;
    for (int d = 1; d < 256; d <<= 1) {
        int add = (t >= d) ? scn[t - d] : 0;
        __syncthreads();
        incl += add;
        scn[t] = incl;
        __syncthreads();
    }
    int ex = incl - s;
    hoff[2 * t] = ex;
    hoff[2 * t + 1] = ex + a0;
    hcur[2 * t] = ex;
    hcur[2 * t + 1] = ex + a0;
    if (t == 255) hoff[MAXB] = cnt;
    // reserve global space: ONE atomic per (tile, nonempty bucket)
    if (a0) gbase[2 * t] = atomicAdd(&gcur[2 * t], a0);
    if (a1) gbase[2 * t + 1] = atomicAdd(&gcur[2 * t + 1], a1);
    __syncthreads();
    // counting-sort into LDS stage
    for (int k = t; k < cnt; k += 256) {
        int d = dst[base + k];
        int p = atomicAdd(&hcur[d >> 8], 1);
        stage[p] = ((unsigned)src[base + k] << 8) | (unsigned)(d & 255);
    }
    __syncthreads();
    // coalesced run copy; bucket of stage slot k via binary search in hoff
    for (int k = t; k < cnt; k += 256) {
        int lo = 0, hi = MAXB;
        while (hi - lo > 1) {
            int mid = (lo + hi) >> 1;
            if (hoff[mid] <= k) lo = mid; else hi = mid;
        }
        binned[gbase[lo] + (k - hoff[lo])] = stage[k];
    }
}

// Exact per-node CSR placement within each coarse bucket (writes stay in a
// hot ~16KB window; 256 LDS cursors, ~16 hits each).
__global__ __launch_bounds__(256) void place_fine(
    const unsigned* __restrict__ binned, const int* __restrict__ offs,
    int* __restrict__ srcs, int n, int E, int NBkt) {
    __shared__ int lcur[256];
    int t = threadIdx.x;
    int b = blockIdx.x;
    int node0 = b << 8;
    int nn = min(256, n - node0);
    lcur[t] = (t < nn) ? offs[node0 + t] : 0;
    __syncthreads();
    int e0 = offs[node0];
    int e1 = (b == NBkt - 1) ? E : offs[node0 + 256];
    for (int k = e0 + t; k < e1; k += 256) {
        unsigned w = binned[k];
        int p = atomicAdd(&lcur[w & 255u], 1);
        srcs[p] = (int)(w >> 8);
    }
}

// h1'[i,f] = dinv[i] * sum_k x[i,k]*W1[k,f]   (x: [n,5], W1: [5,64])
__global__ void transform1(const float* __restrict__ x, const float* __restrict__ W1,
                           const float* __restrict__ dinv, float* __restrict__ h, int n) {
    __shared__ float w[320];
    int t = threadIdx.x;
    w[t] = W1[t];
    if (t < 64) w[t + 256] = W1[t + 256];
    __syncthreads();
    int idx = blockIdx.x * 256 + t;
    int i = idx >> 6, f = idx & 63;
    if (i < n) {
        float acc = 0.f;
#pragma unroll
        for (int k = 0; k < 5; ++k) acc += x[i * 5 + k] * w[k * 64 + f];
        h[idx] = acc * dinv[i];
    }
}

// out[i,f] = relu(dinv[i]*(h'[i,f] + sum_{e:dst=i} h'[src,f]) + b[f])
template <int F>
__global__ void aggregate(const float* __restrict__ h, const int* __restrict__ srcs,
                          const int* __restrict__ offs, const int* __restrict__ deg,
                          const float* __restrict__ dinv, const float* __restrict__ bias,
                          float* __restrict__ out, int n) {
    int idx = blockIdx.x * blockDim.x + threadIdx.x;
    int i = idx / F, f = idx % F;
    if (i >= n) return;
    float acc = h[(size_t)i * F + f];  // self-loop term (pre-scaled)
    int off = offs[i], cnt = deg[i];
    int p = 0;
    for (; p + 4 <= cnt; p += 4) {
        int s0 = srcs[off + p + 0];
        int s1 = srcs[off + p + 1];
        int s2 = srcs[off + p + 2];
        int s3 = srcs[off + p + 3];
        float a0 = h[(size_t)s0 * F + f];
        float a1 = h[(size_t)s1 * F + f];
        float a2 = h[(size_t)s2 * F + f];
        float a3 = h[(size_t)s3 * F + f];
        acc += a0 + a1 + a2 + a3;
    }
    for (; p < cnt; ++p) acc += h[(size_t)srcs[off + p] * F + f];
    float v = dinv[i] * acc + bias[f];
    out[idx] = fmaxf(v, 0.0f);
}

// h2'[i,g] = dinv[i] * sum_k x1[i,k]*W2[k,g]   (x1: [n,64], W2: [64,32])
__global__ void transform2(const float* __restrict__ x1, const float* __restrict__ W2,
                           const float* __restrict__ dinv, float* __restrict__ h2, int n) {
    __shared__ float ws[64 * 32];
    __shared__ float xs[8 * 64];
    int t = threadIdx.x;
#pragma unroll
    for (int k = 0; k < 8; ++k) ws[t + k * 256] = W2[t + k * 256];
    int blockNode = blockIdx.x * 8;
    int g0 = blockNode * 64;
    if (g0 + t < n * 64) xs[t] = x1[g0 + t];
    if (g0 + 256 + t < n * 64) xs[t + 256] = x1[g0 + 256 + t];
    __syncthreads();
    int li = t >> 5, g = t & 31;
    int i = blockNode + li;
    if (i >= n) return;
    float acc = 0.f;
#pragma unroll
    for (int k = 0; k < 64; ++k) acc += xs[li * 64 + k] * ws[k * 32 + g];
    h2[(size_t)i * 32 + g] = acc * dinv[i];
}

// x3 = relu(x2@fcW1 + fcb1); out = x3@fcW2 + fcb2   (per-node thread)
__global__ void fc_head(const float* __restrict__ x2, const float* __restrict__ fcW1,
                        const float* __restrict__ fcb1, const float* __restrict__ fcW2,
                        const float* __restrict__ fcb2, float* __restrict__ out, int n) {
    __shared__ float w1s[512];
    __shared__ float w2s[32];
    __shared__ float b1s[16];
    __shared__ float b2s[2];
    int t = threadIdx.x;
    w1s[t] = fcW1[t];
    w1s[t + 256] = fcW1[t + 256];
    if (t < 32) w2s[t] = fcW2[t];
    if (t < 16) b1s[t] = fcb1[t];
    if (t < 2) b2s[t] = fcb2[t];
    __syncthreads();
    int i = blockIdx.x * 256 + t;
    if (i >= n) return;
    float r[32];
    const float4* xv = (const float4*)(x2 + (size_t)i * 32);
#pragma unroll
    for (int q = 0; q < 8; ++q) {
        float4 v = xv[q];
        r[4 * q + 0] = v.x; r[4 * q + 1] = v.y;
        r[4 * q + 2] = v.z; r[4 * q + 3] = v.w;
    }
    float x3[16];
#pragma unroll
    for (int j = 0; j < 16; ++j) {
        float a = b1s[j];
#pragma unroll
        for (int k = 0; k < 32; ++k) a += r[k] * w1s[k * 16 + j];
        x3[j] = fmaxf(a, 0.f);
    }
#pragma unroll
    for (int o = 0; o < 2; ++o) {
        float a = b2s[o];
#pragma unroll
        for (int j = 0; j < 16; ++j) a += x3[j] * w2s[j * 2 + o];
        out[(size_t)i * 2 + o] = a;
    }
}

extern "C" void kernel_launch(void* const* d_in, const int* in_sizes, int n_in,
                              void* d_out, int out_size, void* d_ws, size_t ws_size,
                              hipStream_t stream) {
    const float* edge_attr = (const float*)d_in[0];
    const int* edge_index  = (const int*)d_in[1];
    const float* W1   = (const float*)d_in[2];
    const float* b1   = (const float*)d_in[3];
    const float* W2   = (const float*)d_in[4];
    const float* b2   = (const float*)d_in[5];
    const float* fcW1 = (const float*)d_in[6];
    const float* fcb1 = (const float*)d_in[7];
    const float* fcW2 = (const float*)d_in[8];
    const float* fcb2 = (const float*)d_in[9];
    float* out = (float*)d_out;

    int n = in_sizes[0] / 5;
    int E = in_sizes[1] / 2;
    int NBkt = (n + 255) >> 8;  // 256-node coarse buckets (391 for n=100000)
    const int* src = edge_index;
    const int* dst = edge_index + E;

    char* ws = (char*)d_ws;
    auto alloc = [&](size_t bytes) {
        char* p = ws;
        ws += (bytes + 255) & ~(size_t)255;
        return p;
    };
    int*   deg   = (int*)alloc((size_t)n * 4);
    int*   offs  = (int*)alloc((size_t)n * 4);
    float* dinv  = (float*)alloc((size_t)n * 4);
    int*   bsums = (int*)alloc(4096);
    int*   gcur  = (int*)alloc((size_t)MAXB * 4);
    int*   srcs  = (int*)alloc((size_t)E * 4);
    float* bufA  = (float*)alloc((size_t)n * 64 * 4);
    float* bufB  = (float*)alloc((size_t)n * 64 * 4);
    // binned aliases bufB: dead before aggregate<64> first writes bufB
    unsigned* binned = (unsigned*)bufB;

    hipMemsetAsync(deg, 0, (size_t)n * sizeof(int), stream);

    int eb = (E + 255) / 256;
    count_deg<<<eb, 256, 0, stream>>>(dst, deg, E);

    int nScanBlocks = (n + 2047) / 2048;  // 49 (must be <= 64)
    scanA<<<nScanBlocks, 256, 0, stream>>>(deg, offs, bsums, n);
    scanB<<<1, 64, 0, stream>>>(bsums, nScanBlocks);
    scanC<<<(n + 255) / 256, 256, 0, stream>>>(offs, bsums, deg, dinv, gcur, n);

    multisplit<<<(E + MS_TILE - 1) / MS_TILE, 256, 0, stream>>>(src, dst, gcur, binned, E);
    place_fine<<<NBkt, 256, 0, stream>>>(binned, offs, srcs, n, E, NBkt);

    transform1<<<(n * 64 + 255) / 256, 256, 0, stream>>>(edge_attr, W1, dinv, bufA, n);
    aggregate<64><<<(n * 64 + 255) / 256, 256, 0, stream>>>(bufA, srcs, offs, deg, dinv,
                                                            b1, bufB, n);
    transform2<<<(n + 7) / 8, 256, 0, stream>>>(bufB, W2, dinv, bufA, n);
    aggregate<32><<<(n * 32 + 255) / 256, 256, 0, stream>>>(bufA, srcs, offs, deg, dinv,
                                                            b2, bufB, n);
    fc_head<<<(n + 255) / 256, 256, 0, stream>>>(bufB, fcW1, fcb1, fcW2, fcb2, out, n);
}

// Round 5
// 277.708 us; speedup vs baseline: 2.3486x; 1.3955x over previous
//
#include <hip/hip_runtime.h>

// ---------------------------------------------------------------------------
// GCN pipeline, round 5:
//   coarse_count (LDS hist, 512 coarse buckets) -> scan_coarse ->
//   multisplit (tile counting sort, coalesced) -> place_fine2 (per-bucket:
//   per-node deg/offs/dinv/y + exact CSR via LDS cursors) ->
//   agg_xin (aggregate in 5-dim input space; L2-resident 3.2MB working set)
//   -> transform1 (z@W1+b, relu) -> transform2 (dinv*out1@W2) ->
//   aggregate<32> -> fc head.
// Round-4 lesson: aggregate<64> fetched 192MB (random 256B gathers from a
// 25.6MB set). Linearity: dinv_i*(sum h'_src)@W1 == (dinv_i*sum dinv_s*x_s)@W1,
// so layer-1 aggregation moves to the 5-dim input space (3.2MB, L2-resident).
// count_deg's 1.6M random atomics + 3 scan kernels replaced by coarse
// histogram + per-bucket LDS count/scan in place_fine2.
// ---------------------------------------------------------------------------

#define MS_TILE 8192
#define MAXB 512  // padded coarse-bucket count (NBkt = ceil(n/256) <= 512)

// per-tile LDS histogram of dst>>8; one global atomic per (tile, bucket)
__global__ __launch_bounds__(256) void coarse_count(const int* __restrict__ dst,
                                                    int* __restrict__ gcount, int E) {
    __shared__ int h[MAXB];
    int t = threadIdx.x;
    h[t] = 0;
    h[t + 256] = 0;
    __syncthreads();
    int base = blockIdx.x * MS_TILE;
    int cnt = min(MS_TILE, E - base);
    for (int k = t; k < cnt; k += 256) atomicAdd(&h[dst[base + k] >> 8], 1);
    __syncthreads();
    if (h[t]) atomicAdd(&gcount[t], h[t]);
    if (h[t + 256]) atomicAdd(&gcount[t + 256], h[t + 256]);
}

// single-block exclusive scan of 512 coarse counts -> gbase, gcur
__global__ __launch_bounds__(256) void scan_coarse(const int* __restrict__ gcount,
                                                   int* __restrict__ gbase,
                                                   int* __restrict__ gcur, int E) {
    __shared__ int scn[256];
    int t = threadIdx.x;
    int a0 = gcount[2 * t], a1 = gcount[2 * t + 1];
    int s = a0 + a1;
    scn[t] = s;
    __syncthreads();
    int incl = s;
    for (int d = 1; d < 256; d <<= 1) {
        int add = (t >= d) ? scn[t - d] : 0;
        __syncthreads();
        incl += add;
        scn[t] = incl;
        __syncthreads();
    }
    int ex = incl - s;
    gbase[2 * t] = ex;
    gbase[2 * t + 1] = ex + a0;
    gcur[2 * t] = ex;
    gcur[2 * t + 1] = ex + a0;
    if (t == 255) gbase[MAXB] = E;
}

// Tile counting-sort into 256-node coarse buckets. Payload: (src<<8)|(dst&255).
__global__ __launch_bounds__(256) void multisplit(
    const int* __restrict__ src, const int* __restrict__ dst,
    int* __restrict__ gcur, unsigned* __restrict__ binned, int E) {
    __shared__ unsigned stage[MS_TILE];
    __shared__ int hist[MAXB];
    __shared__ int hoff[MAXB + 1];
    __shared__ int hcur[MAXB];
    __shared__ int gbase[MAXB];
    __shared__ int scn[256];
    int t = threadIdx.x;
    int base = blockIdx.x * MS_TILE;
    int cnt = min(MS_TILE, E - base);

    hist[2 * t] = 0;
    hist[2 * t + 1] = 0;
    __syncthreads();
    for (int k = t; k < cnt; k += 256)
        atomicAdd(&hist[dst[base + k] >> 8], 1);
    __syncthreads();
    int a0 = hist[2 * t], a1 = hist[2 * t + 1];
    int s = a0 + a1;
    scn[t] = s;
    __syncthreads();
    int incl = s;
    for (int d = 1; d < 256; d <<= 1) {
        int add = (t >= d) ? scn[t - d] : 0;
        __syncthreads();
        incl += add;
        scn[t] = incl;
        __syncthreads();
    }
    int ex = incl - s;
    hoff[2 * t] = ex;
    hoff[2 * t + 1] = ex + a0;
    hcur[2 * t] = ex;
    hcur[2 * t + 1] = ex + a0;
    if (t == 255) hoff[MAXB] = cnt;
    if (a0) gbase[2 * t] = atomicAdd(&gcur[2 * t], a0);
    if (a1) gbase[2 * t + 1] = atomicAdd(&gcur[2 * t + 1], a1);
    __syncthreads();
    for (int k = t; k < cnt; k += 256) {
        int d = dst[base + k];
        int p = atomicAdd(&hcur[d >> 8], 1);
        stage[p] = ((unsigned)src[base + k] << 8) | (unsigned)(d & 255);
    }
    __syncthreads();
    for (int k = t; k < cnt; k += 256) {
        int lo = 0, hi = MAXB;
        while (hi - lo > 1) {
            int mid = (lo + hi) >> 1;
            if (hoff[mid] <= k) lo = mid; else hi = mid;
        }
        binned[gbase[lo] + (k - hoff[lo])] = stage[k];
    }
}

// Per coarse bucket: per-node deg via LDS count, LDS scan -> offs, dinv,
// y[i,:] = dinv[i]*x[i,:] (padded to 8 floats), then exact CSR scatter.
__global__ __launch_bounds__(256) void place_fine2(
    const unsigned* __restrict__ binned, const int* __restrict__ gbase,
    const float* __restrict__ x, int* __restrict__ offs, int* __restrict__ deg,
    float* __restrict__ dinv, float* __restrict__ y, int* __restrict__ srcs, int n) {
    __shared__ int cnt[256];
    __shared__ int scn[256];
    __shared__ int lcur[256];
    int t = threadIdx.x, b = blockIdx.x;
    int node0 = b << 8;
    int nn = min(256, n - node0);
    int e0 = gbase[b], e1 = gbase[b + 1];
    cnt[t] = 0;
    __syncthreads();
    for (int k = e0 + t; k < e1; k += 256) atomicAdd(&cnt[binned[k] & 255u], 1);
    __syncthreads();
    int c = cnt[t];
    scn[t] = c;
    __syncthreads();
    int incl = c;
    for (int d = 1; d < 256; d <<= 1) {
        int add = (t >= d) ? scn[t - d] : 0;
        __syncthreads();
        incl += add;
        scn[t] = incl;
        __syncthreads();
    }
    int myoff = e0 + (incl - c);
    lcur[t] = myoff;
    if (t < nn) {
        int node = node0 + t;
        offs[node] = myoff;
        deg[node] = c;
        float di = 1.0f / sqrtf((float)(c + 1));  // +1 self loop
        dinv[node] = di;
        const float* xr = x + (size_t)node * 5;
        float4 a = {xr[0] * di, xr[1] * di, xr[2] * di, xr[3] * di};
        float4 bq = {xr[4] * di, 0.f, 0.f, 0.f};
        *(float4*)(y + (size_t)node * 8) = a;
        *(float4*)(y + (size_t)node * 8 + 4) = bq;
    }
    __syncthreads();
    for (int k = e0 + t; k < e1; k += 256) {
        unsigned w = binned[k];
        int p = atomicAdd(&lcur[w & 255u], 1);
        srcs[p] = (int)(w >> 8);
    }
}

// z[i,:] = dinv[i]*(y[i,:] + sum_{e:dst=i} y[src,:])  (8-float padded rows,
// 3.2MB working set -> L2-resident random gathers)
__global__ void agg_xin(const float* __restrict__ y, const int* __restrict__ srcs,
                        const int* __restrict__ offs, const int* __restrict__ deg,
                        const float* __restrict__ dinv, float* __restrict__ z, int n) {
    int i = blockIdx.x * blockDim.x + threadIdx.x;
    if (i >= n) return;
    const float4* yv = (const float4*)y;
    float4 a = yv[(size_t)i * 2];
    float4 b = yv[(size_t)i * 2 + 1];
    int off = offs[i], cnt = deg[i];
    int p = 0;
    for (; p + 2 <= cnt; p += 2) {
        int s0 = srcs[off + p], s1 = srcs[off + p + 1];
        float4 v0 = yv[(size_t)s0 * 2];
        float4 w0 = yv[(size_t)s0 * 2 + 1];
        float4 v1 = yv[(size_t)s1 * 2];
        float4 w1 = yv[(size_t)s1 * 2 + 1];
        a.x += v0.x + v1.x; a.y += v0.y + v1.y; a.z += v0.z + v1.z; a.w += v0.w + v1.w;
        b.x += w0.x + w1.x;
    }
    if (p < cnt) {
        int s0 = srcs[off + p];
        float4 v0 = yv[(size_t)s0 * 2];
        float w0 = y[(size_t)s0 * 8 + 4];
        a.x += v0.x; a.y += v0.y; a.z += v0.z; a.w += v0.w;
        b.x += w0;
    }
    float di = dinv[i];
    float4 oa = {a.x * di, a.y * di, a.z * di, a.w * di};
    float4 ob = {b.x * di, 0.f, 0.f, 0.f};
    float4* zv = (float4*)z;
    zv[(size_t)i * 2] = oa;
    zv[(size_t)i * 2 + 1] = ob;
}

// out1[i,f] = relu(sum_k z[i,k]*W1[k,f] + b1[f])   (z: [n,8] (5 used), W1: [5,64])
__global__ void transform1(const float* __restrict__ z, const float* __restrict__ W1,
                           const float* __restrict__ b1, float* __restrict__ out1, int n) {
    __shared__ float w[320];
    __shared__ float bs[64];
    int t = threadIdx.x;
    w[t] = W1[t];
    if (t < 64) {
        w[t + 256] = W1[t + 256];
        bs[t] = b1[t];
    }
    __syncthreads();
    int idx = blockIdx.x * 256 + t;
    int i = idx >> 6, f = idx & 63;
    if (i < n) {
        const float* zr = z + (size_t)i * 8;
        float acc = bs[f];
#pragma unroll
        for (int k = 0; k < 5; ++k) acc += zr[k] * w[k * 64 + f];
        out1[idx] = fmaxf(acc, 0.0f);
    }
}

// h2'[i,g] = dinv[i] * sum_k x1[i,k]*W2[k,g]   (x1: [n,64], W2: [64,32])
__global__ void transform2(const float* __restrict__ x1, const float* __restrict__ W2,
                           const float* __restrict__ dinv, float* __restrict__ h2, int n) {
    __shared__ float ws[64 * 32];
    __shared__ float xs[8 * 64];
    int t = threadIdx.x;
#pragma unroll
    for (int k = 0; k < 8; ++k) ws[t + k * 256] = W2[t + k * 256];
    int blockNode = blockIdx.x * 8;
    int g0 = blockNode * 64;
    if (g0 + t < n * 64) xs[t] = x1[g0 + t];
    if (g0 + 256 + t < n * 64) xs[t + 256] = x1[g0 + 256 + t];
    __syncthreads();
    int li = t >> 5, g = t & 31;
    int i = blockNode + li;
    if (i >= n) return;
    float acc = 0.f;
#pragma unroll
    for (int k = 0; k < 64; ++k) acc += xs[li * 64 + k] * ws[k * 32 + g];
    h2[(size_t)i * 32 + g] = acc * dinv[i];
}

// out[i,f] = relu(dinv[i]*(h'[i,f] + sum_{e:dst=i} h'[src,f]) + b[f])
template <int F>
__global__ void aggregate(const float* __restrict__ h, const int* __restrict__ srcs,
                          const int* __restrict__ offs, const int* __restrict__ deg,
                          const float* __restrict__ dinv, const float* __restrict__ bias,
                          float* __restrict__ out, int n) {
    int idx = blockIdx.x * blockDim.x + threadIdx.x;
    int i = idx / F, f = idx % F;
    if (i >= n) return;
    float acc = h[(size_t)i * F + f];  // self-loop term (pre-scaled)
    int off = offs[i], cnt = deg[i];
    int p = 0;
    for (; p + 4 <= cnt; p += 4) {
        int s0 = srcs[off + p + 0];
        int s1 = srcs[off + p + 1];
        int s2 = srcs[off + p + 2];
        int s3 = srcs[off + p + 3];
        float a0 = h[(size_t)s0 * F + f];
        float a1 = h[(size_t)s1 * F + f];
        float a2 = h[(size_t)s2 * F + f];
        float a3 = h[(size_t)s3 * F + f];
        acc += a0 + a1 + a2 + a3;
    }
    for (; p < cnt; ++p) acc += h[(size_t)srcs[off + p] * F + f];
    float v = dinv[i] * acc + bias[f];
    out[idx] = fmaxf(v, 0.0f);
}

// x3 = relu(x2@fcW1 + fcb1); out = x3@fcW2 + fcb2   (per-node thread)
__global__ void fc_head(const float* __restrict__ x2, const float* __restrict__ fcW1,
                        const float* __restrict__ fcb1, const float* __restrict__ fcW2,
                        const float* __restrict__ fcb2, float* __restrict__ out, int n) {
    __shared__ float w1s[512];
    __shared__ float w2s[32];
    __shared__ float b1s[16];
    __shared__ float b2s[2];
    int t = threadIdx.x;
    w1s[t] = fcW1[t];
    w1s[t + 256] = fcW1[t + 256];
    if (t < 32) w2s[t] = fcW2[t];
    if (t < 16) b1s[t] = fcb1[t];
    if (t < 2) b2s[t] = fcb2[t];
    __syncthreads();
    int i = blockIdx.x * 256 + t;
    if (i >= n) return;
    float r[32];
    const float4* xv = (const float4*)(x2 + (size_t)i * 32);
#pragma unroll
    for (int q = 0; q < 8; ++q) {
        float4 v = xv[q];
        r[4 * q + 0] = v.x; r[4 * q + 1] = v.y;
        r[4 * q + 2] = v.z; r[4 * q + 3] = v.w;
    }
    float x3[16];
#pragma unroll
    for (int j = 0; j < 16; ++j) {
        float a = b1s[j];
#pragma unroll
        for (int k = 0; k < 32; ++k) a += r[k] * w1s[k * 16 + j];
        x3[j] = fmaxf(a, 0.f);
    }
#pragma unroll
    for (int o = 0; o < 2; ++o) {
        float a = b2s[o];
#pragma unroll
        for (int j = 0; j < 16; ++j) a += x3[j] * w2s[j * 2 + o];
        out[(size_t)i * 2 + o] = a;
    }
}

extern "C" void kernel_launch(void* const* d_in, const int* in_sizes, int n_in,
                              void* d_out, int out_size, void* d_ws, size_t ws_size,
                              hipStream_t stream) {
    const float* edge_attr = (const float*)d_in[0];
    const int* edge_index  = (const int*)d_in[1];
    const float* W1   = (const float*)d_in[2];
    const float* b1   = (const float*)d_in[3];
    const float* W2   = (const float*)d_in[4];
    const float* b2   = (const float*)d_in[5];
    const float* fcW1 = (const float*)d_in[6];
    const float* fcb1 = (const float*)d_in[7];
    const float* fcW2 = (const float*)d_in[8];
    const float* fcb2 = (const float*)d_in[9];
    float* out = (float*)d_out;

    int n = in_sizes[0] / 5;
    int E = in_sizes[1] / 2;
    int NBkt = (n + 255) >> 8;  // 391 for n=100000 (<= MAXB)
    const int* src = edge_index;
    const int* dst = edge_index + E;

    char* ws = (char*)d_ws;
    auto alloc = [&](size_t bytes) {
        char* p = ws;
        ws += (bytes + 255) & ~(size_t)255;
        return p;
    };
    int*   deg    = (int*)alloc((size_t)n * 4);
    int*   offs   = (int*)alloc((size_t)n * 4);
    float* dinv   = (float*)alloc((size_t)n * 4);
    int*   gcount = (int*)alloc((size_t)MAXB * 4);
    int*   gbase  = (int*)alloc((size_t)(MAXB + 1) * 4);
    int*   gcur   = (int*)alloc((size_t)MAXB * 4);
    int*   srcs   = (int*)alloc((size_t)E * 4);
    float* y      = (float*)alloc((size_t)n * 8 * 4);
    float* z      = (float*)alloc((size_t)n * 8 * 4);
    float* bufA   = (float*)alloc((size_t)n * 64 * 4);  // out1; later out2
    float* bufB   = (float*)alloc((size_t)n * 32 * 4);  // h2'
    // binned aliases bufA: dead after place_fine2, before transform1 writes
    unsigned* binned = (unsigned*)bufA;

    hipMemsetAsync(gcount, 0, (size_t)MAXB * 4, stream);

    int nTiles = (E + MS_TILE - 1) / MS_TILE;
    coarse_count<<<nTiles, 256, 0, stream>>>(dst, gcount, E);
    scan_coarse<<<1, 256, 0, stream>>>(gcount, gbase, gcur, E);
    multisplit<<<nTiles, 256, 0, stream>>>(src, dst, gcur, binned, E);
    place_fine2<<<NBkt, 256, 0, stream>>>(binned, gbase, edge_attr, offs, deg, dinv,
                                          y, srcs, n);

    agg_xin<<<(n + 255) / 256, 256, 0, stream>>>(y, srcs, offs, deg, dinv, z, n);
    transform1<<<(n * 64 + 255) / 256, 256, 0, stream>>>(z, W1, b1, bufA, n);
    transform2<<<(n + 7) / 8, 256, 0, stream>>>(bufA, W2, dinv, bufB, n);
    aggregate<32><<<(n * 32 + 255) / 256, 256, 0, stream>>>(bufB, srcs, offs, deg, dinv,
                                                            b2, bufA, n);
    fc_head<<<(n + 255) / 256, 256, 0, stream>>>(bufA, fcW1, fcb1, fcW2, fcb2, out, n);
}

// Round 6
// 239.276 us; speedup vs baseline: 2.7258x; 1.1606x over previous
//
#include <hip/hip_runtime.h>

// ---------------------------------------------------------------------------
// GCN pipeline, round 6:
//   histA (per-tile LDS hist -> histG[tile][512], coalesced, NO global
//   atomics) -> scanTiles (per-bucket block scans counts across tiles ->
//   offsG + bucketTotal) -> scanBase (bucket bases = gbase) -> multisplit2
//   (deterministic counting sort: load count/offset rows, LDS sort with
//   stored bucket ids, coalesced run copy) -> place_fine2 (per-bucket
//   deg/offs/dinv/y + exact CSR) -> agg_xin (5-dim L2-resident aggregate)
//   -> transform1 -> transform2 -> aggregate<32> -> fc head.
// Round-5 lesson: multisplit at 8192-edge tiles = 196 blocks = 7% occupancy,
// latency-bound (61us), plus cross-XCD global-atomic reservation chains.
// Radix-style precomputed offsets remove all global atomics and quadruple
// the grid.
// ---------------------------------------------------------------------------

#define MS_TILE 2048
#define MAXB 512  // padded coarse-bucket count (NBkt = ceil(n/256) <= 512)

// per-tile LDS histogram of dst>>8 -> histG[tile*512 + b] (coalesced rows)
__global__ __launch_bounds__(256) void histA(const int* __restrict__ dst,
                                             int* __restrict__ histG, int E) {
    __shared__ int h[MAXB];
    int t = threadIdx.x;
    h[t] = 0;
    h[t + 256] = 0;
    __syncthreads();
    int base = blockIdx.x * MS_TILE;
    int cnt = min(MS_TILE, E - base);
    for (int k = t; k < cnt; k += 256) atomicAdd(&h[dst[base + k] >> 8], 1);
    __syncthreads();
    histG[blockIdx.x * MAXB + t] = h[t];
    histG[blockIdx.x * MAXB + 256 + t] = h[t + 256];
}

// one block per bucket b: exclusive scan of histG[.][b] across tiles ->
// offsG[tile*512+b]; bucket total -> bucketTotal[b]
__global__ __launch_bounds__(256) void scanTiles(const int* __restrict__ histG,
                                                 int* __restrict__ offsG,
                                                 int* __restrict__ bucketTotal,
                                                 int nTiles) {
    __shared__ int scn[256];
    int b = blockIdx.x, t = threadIdx.x;
    int run = 0;
    for (int base = 0; base < nTiles; base += 256) {
        int idx = base + t;
        int v = (idx < nTiles) ? histG[idx * MAXB + b] : 0;
        scn[t] = v;
        __syncthreads();
        int incl = v;
        for (int d = 1; d < 256; d <<= 1) {
            int add = (t >= d) ? scn[t - d] : 0;
            __syncthreads();
            incl += add;
            scn[t] = incl;
            __syncthreads();
        }
        if (idx < nTiles) offsG[idx * MAXB + b] = incl - v + run;
        run += scn[255];  // chunk total (valid: last sync above)
        __syncthreads();  // protect scn before next chunk overwrites
    }
    if (t == 0) bucketTotal[b] = run;
}

// single-block exclusive scan of 512 bucket totals -> gbase[0..512]
__global__ __launch_bounds__(256) void scanBase(const int* __restrict__ bucketTotal,
                                                int* __restrict__ gbase, int E) {
    __shared__ int scn[256];
    int t = threadIdx.x;
    int a0 = bucketTotal[2 * t], a1 = bucketTotal[2 * t + 1];
    int s = a0 + a1;
    scn[t] = s;
    __syncthreads();
    int incl = s;
    for (int d = 1; d < 256; d <<= 1) {
        int add = (t >= d) ? scn[t - d] : 0;
        __syncthreads();
        incl += add;
        scn[t] = incl;
        __syncthreads();
    }
    int ex = incl - s;
    gbase[2 * t] = ex;
    gbase[2 * t + 1] = ex + a0;
    if (t == 255) gbase[MAXB] = E;
}

// Deterministic tile counting-sort. Payload: (src<<8)|(dst&255).
__global__ __launch_bounds__(256) void multisplit2(
    const int* __restrict__ src, const int* __restrict__ dst,
    const int* __restrict__ histG, const int* __restrict__ offsG,
    const int* __restrict__ gbase, unsigned* __restrict__ binned, int E) {
    __shared__ unsigned stage[MS_TILE];
    __shared__ unsigned short sb[MS_TILE];
    __shared__ int hoff[MAXB + 1];
    __shared__ int hcur[MAXB];
    __shared__ int gb[MAXB];
    __shared__ int scn[256];
    int t = threadIdx.x;
    int tile = blockIdx.x;
    int base = tile * MS_TILE;
    int cnt = min(MS_TILE, E - base);

    int a0 = histG[tile * MAXB + 2 * t];
    int a1 = histG[tile * MAXB + 2 * t + 1];
    gb[2 * t] = gbase[2 * t] + offsG[tile * MAXB + 2 * t];
    gb[2 * t + 1] = gbase[2 * t + 1] + offsG[tile * MAXB + 2 * t + 1];
    int s = a0 + a1;
    scn[t] = s;
    __syncthreads();
    int incl = s;
    for (int d = 1; d < 256; d <<= 1) {
        int add = (t >= d) ? scn[t - d] : 0;
        __syncthreads();
        incl += add;
        scn[t] = incl;
        __syncthreads();
    }
    int ex = incl - s;
    hoff[2 * t] = ex;
    hoff[2 * t + 1] = ex + a0;
    hcur[2 * t] = ex;
    hcur[2 * t + 1] = ex + a0;
    if (t == 255) hoff[MAXB] = cnt;
    __syncthreads();
    // counting-sort into LDS stage, remembering each slot's bucket
    for (int k = t; k < cnt; k += 256) {
        int d = dst[base + k];
        int b = d >> 8;
        int p = atomicAdd(&hcur[b], 1);
        stage[p] = ((unsigned)src[base + k] << 8) | (unsigned)(d & 255);
        sb[p] = (unsigned short)b;
    }
    __syncthreads();
    // coalesced run copy to exact global slots
    for (int k = t; k < cnt; k += 256) {
        int b = sb[k];
        binned[gb[b] + (k - hoff[b])] = stage[k];
    }
}

// Per coarse bucket: per-node deg via LDS count, LDS scan -> offs, dinv,
// y[i,:] = dinv[i]*x[i,:] (padded to 8 floats), then exact CSR scatter.
__global__ __launch_bounds__(256) void place_fine2(
    const unsigned* __restrict__ binned, const int* __restrict__ gbase,
    const float* __restrict__ x, int* __restrict__ offs, int* __restrict__ deg,
    float* __restrict__ dinv, float* __restrict__ y, int* __restrict__ srcs, int n) {
    __shared__ int cnt[256];
    __shared__ int scn[256];
    __shared__ int lcur[256];
    int t = threadIdx.x, b = blockIdx.x;
    int node0 = b << 8;
    int nn = min(256, n - node0);
    int e0 = gbase[b], e1 = gbase[b + 1];
    cnt[t] = 0;
    __syncthreads();
    for (int k = e0 + t; k < e1; k += 256) atomicAdd(&cnt[binned[k] & 255u], 1);
    __syncthreads();
    int c = cnt[t];
    scn[t] = c;
    __syncthreads();
    int incl = c;
    for (int d = 1; d < 256; d <<= 1) {
        int add = (t >= d) ? scn[t - d] : 0;
        __syncthreads();
        incl += add;
        scn[t] = incl;
        __syncthreads();
    }
    int myoff = e0 + (incl - c);
    lcur[t] = myoff;
    if (t < nn) {
        int node = node0 + t;
        offs[node] = myoff;
        deg[node] = c;
        float di = 1.0f / sqrtf((float)(c + 1));  // +1 self loop
        dinv[node] = di;
        const float* xr = x + (size_t)node * 5;
        float4 a = {xr[0] * di, xr[1] * di, xr[2] * di, xr[3] * di};
        float4 bq = {xr[4] * di, 0.f, 0.f, 0.f};
        *(float4*)(y + (size_t)node * 8) = a;
        *(float4*)(y + (size_t)node * 8 + 4) = bq;
    }
    __syncthreads();
    for (int k = e0 + t; k < e1; k += 256) {
        unsigned w = binned[k];
        int p = atomicAdd(&lcur[w & 255u], 1);
        srcs[p] = (int)(w >> 8);
    }
}

// z[i,:] = dinv[i]*(y[i,:] + sum_{e:dst=i} y[src,:])  (8-float padded rows,
// 3.2MB working set -> L2-resident random gathers)
__global__ void agg_xin(const float* __restrict__ y, const int* __restrict__ srcs,
                        const int* __restrict__ offs, const int* __restrict__ deg,
                        const float* __restrict__ dinv, float* __restrict__ z, int n) {
    int i = blockIdx.x * blockDim.x + threadIdx.x;
    if (i >= n) return;
    const float4* yv = (const float4*)y;
    float4 a = yv[(size_t)i * 2];
    float4 b = yv[(size_t)i * 2 + 1];
    int off = offs[i], cnt = deg[i];
    int p = 0;
    for (; p + 2 <= cnt; p += 2) {
        int s0 = srcs[off + p], s1 = srcs[off + p + 1];
        float4 v0 = yv[(size_t)s0 * 2];
        float4 w0 = yv[(size_t)s0 * 2 + 1];
        float4 v1 = yv[(size_t)s1 * 2];
        float4 w1 = yv[(size_t)s1 * 2 + 1];
        a.x += v0.x + v1.x; a.y += v0.y + v1.y; a.z += v0.z + v1.z; a.w += v0.w + v1.w;
        b.x += w0.x + w1.x;
    }
    if (p < cnt) {
        int s0 = srcs[off + p];
        float4 v0 = yv[(size_t)s0 * 2];
        float w0 = y[(size_t)s0 * 8 + 4];
        a.x += v0.x; a.y += v0.y; a.z += v0.z; a.w += v0.w;
        b.x += w0;
    }
    float di = dinv[i];
    float4 oa = {a.x * di, a.y * di, a.z * di, a.w * di};
    float4 ob = {b.x * di, 0.f, 0.f, 0.f};
    float4* zv = (float4*)z;
    zv[(size_t)i * 2] = oa;
    zv[(size_t)i * 2 + 1] = ob;
}

// out1[i,f] = relu(sum_k z[i,k]*W1[k,f] + b1[f])   (z: [n,8] (5 used), W1: [5,64])
__global__ void transform1(const float* __restrict__ z, const float* __restrict__ W1,
                           const float* __restrict__ b1, float* __restrict__ out1, int n) {
    __shared__ float w[320];
    __shared__ float bs[64];
    int t = threadIdx.x;
    w[t] = W1[t];
    if (t < 64) {
        w[t + 256] = W1[t + 256];
        bs[t] = b1[t];
    }
    __syncthreads();
    int idx = blockIdx.x * 256 + t;
    int i = idx >> 6, f = idx & 63;
    if (i < n) {
        const float* zr = z + (size_t)i * 8;
        float acc = bs[f];
#pragma unroll
        for (int k = 0; k < 5; ++k) acc += zr[k] * w[k * 64 + f];
        out1[idx] = fmaxf(acc, 0.0f);
    }
}

// h2'[i,g] = dinv[i] * sum_k x1[i,k]*W2[k,g]   (x1: [n,64], W2: [64,32])
__global__ void transform2(const float* __restrict__ x1, const float* __restrict__ W2,
                           const float* __restrict__ dinv, float* __restrict__ h2, int n) {
    __shared__ float ws[64 * 32];
    __shared__ float xs[8 * 64];
    int t = threadIdx.x;
#pragma unroll
    for (int k = 0; k < 8; ++k) ws[t + k * 256] = W2[t + k * 256];
    int blockNode = blockIdx.x * 8;
    int g0 = blockNode * 64;
    if (g0 + t < n * 64) xs[t] = x1[g0 + t];
    if (g0 + 256 + t < n * 64) xs[t + 256] = x1[g0 + 256 + t];
    __syncthreads();
    int li = t >> 5, g = t & 31;
    int i = blockNode + li;
    if (i >= n) return;
    float acc = 0.f;
#pragma unroll
    for (int k = 0; k < 64; ++k) acc += xs[li * 64 + k] * ws[k * 32 + g];
    h2[(size_t)i * 32 + g] = acc * dinv[i];
}

// out[i,f] = relu(dinv[i]*(h'[i,f] + sum_{e:dst=i} h'[src,f]) + b[f])
template <int F>
__global__ void aggregate(const float* __restrict__ h, const int* __restrict__ srcs,
                          const int* __restrict__ offs, const int* __restrict__ deg,
                          const float* __restrict__ dinv, const float* __restrict__ bias,
                          float* __restrict__ out, int n) {
    int idx = blockIdx.x * blockDim.x + threadIdx.x;
    int i = idx / F, f = idx % F;
    if (i >= n) return;
    float acc = h[(size_t)i * F + f];  // self-loop term (pre-scaled)
    int off = offs[i], cnt = deg[i];
    int p = 0;
    for (; p + 4 <= cnt; p += 4) {
        int s0 = srcs[off + p + 0];
        int s1 = srcs[off + p + 1];
        int s2 = srcs[off + p + 2];
        int s3 = srcs[off + p + 3];
        float a0 = h[(size_t)s0 * F + f];
        float a1 = h[(size_t)s1 * F + f];
        float a2 = h[(size_t)s2 * F + f];
        float a3 = h[(size_t)s3 * F + f];
        acc += a0 + a1 + a2 + a3;
    }
    for (; p < cnt; ++p) acc += h[(size_t)srcs[off + p] * F + f];
    float v = dinv[i] * acc + bias[f];
    out[idx] = fmaxf(v, 0.0f);
}

// x3 = relu(x2@fcW1 + fcb1); out = x3@fcW2 + fcb2   (per-node thread)
__global__ void fc_head(const float* __restrict__ x2, const float* __restrict__ fcW1,
                        const float* __restrict__ fcb1, const float* __restrict__ fcW2,
                        const float* __restrict__ fcb2, float* __restrict__ out, int n) {
    __shared__ float w1s[512];
    __shared__ float w2s[32];
    __shared__ float b1s[16];
    __shared__ float b2s[2];
    int t = threadIdx.x;
    w1s[t] = fcW1[t];
    w1s[t + 256] = fcW1[t + 256];
    if (t < 32) w2s[t] = fcW2[t];
    if (t < 16) b1s[t] = fcb1[t];
    if (t < 2) b2s[t] = fcb2[t];
    __syncthreads();
    int i = blockIdx.x * 256 + t;
    if (i >= n) return;
    float r[32];
    const float4* xv = (const float4*)(x2 + (size_t)i * 32);
#pragma unroll
    for (int q = 0; q < 8; ++q) {
        float4 v = xv[q];
        r[4 * q + 0] = v.x; r[4 * q + 1] = v.y;
        r[4 * q + 2] = v.z; r[4 * q + 3] = v.w;
    }
    float x3[16];
#pragma unroll
    for (int j = 0; j < 16; ++j) {
        float a = b1s[j];
#pragma unroll
        for (int k = 0; k < 32; ++k) a += r[k] * w1s[k * 16 + j];
        x3[j] = fmaxf(a, 0.f);
    }
#pragma unroll
    for (int o = 0; o < 2; ++o) {
        float a = b2s[o];
#pragma unroll
        for (int j = 0; j < 16; ++j) a += x3[j] * w2s[j * 2 + o];
        out[(size_t)i * 2 + o] = a;
    }
}

extern "C" void kernel_launch(void* const* d_in, const int* in_sizes, int n_in,
                              void* d_out, int out_size, void* d_ws, size_t ws_size,
                              hipStream_t stream) {
    const float* edge_attr = (const float*)d_in[0];
    const int* edge_index  = (const int*)d_in[1];
    const float* W1   = (const float*)d_in[2];
    const float* b1   = (const float*)d_in[3];
    const float* W2   = (const float*)d_in[4];
    const float* b2   = (const float*)d_in[5];
    const float* fcW1 = (const float*)d_in[6];
    const float* fcb1 = (const float*)d_in[7];
    const float* fcW2 = (const float*)d_in[8];
    const float* fcb2 = (const float*)d_in[9];
    float* out = (float*)d_out;

    int n = in_sizes[0] / 5;
    int E = in_sizes[1] / 2;
    int NBkt = (n + 255) >> 8;  // 391 for n=100000 (<= MAXB)
    int nTiles = (E + MS_TILE - 1) / MS_TILE;  // 782
    const int* src = edge_index;
    const int* dst = edge_index + E;

    char* ws = (char*)d_ws;
    auto alloc = [&](size_t bytes) {
        char* p = ws;
        ws += (bytes + 255) & ~(size_t)255;
        return p;
    };
    int*   deg    = (int*)alloc((size_t)n * 4);
    int*   offs   = (int*)alloc((size_t)n * 4);
    float* dinv   = (float*)alloc((size_t)n * 4);
    int*   histG  = (int*)alloc((size_t)nTiles * MAXB * 4);
    int*   offsG  = (int*)alloc((size_t)nTiles * MAXB * 4);
    int*   btot   = (int*)alloc((size_t)MAXB * 4);
    int*   gbase  = (int*)alloc((size_t)(MAXB + 1) * 4);
    int*   srcs   = (int*)alloc((size_t)E * 4);
    float* y      = (float*)alloc((size_t)n * 8 * 4);
    float* z      = (float*)alloc((size_t)n * 8 * 4);
    float* bufA   = (float*)alloc((size_t)n * 64 * 4);  // out1; later out2
    float* bufB   = (float*)alloc((size_t)n * 32 * 4);  // h2'
    // binned aliases bufA: dead after place_fine2, before transform1 writes
    unsigned* binned = (unsigned*)bufA;

    histA<<<nTiles, 256, 0, stream>>>(dst, histG, E);
    scanTiles<<<MAXB, 256, 0, stream>>>(histG, offsG, btot, nTiles);
    scanBase<<<1, 256, 0, stream>>>(btot, gbase, E);
    multisplit2<<<nTiles, 256, 0, stream>>>(src, dst, histG, offsG, gbase, binned, E);
    place_fine2<<<NBkt, 256, 0, stream>>>(binned, gbase, edge_attr, offs, deg, dinv,
                                          y, srcs, n);

    agg_xin<<<(n + 255) / 256, 256, 0, stream>>>(y, srcs, offs, deg, dinv, z, n);
    transform1<<<(n * 64 + 255) / 256, 256, 0, stream>>>(z, W1, b1, bufA, n);
    transform2<<<(n + 7) / 8, 256, 0, stream>>>(bufA, W2, dinv, bufB, n);
    aggregate<32><<<(n * 32 + 255) / 256, 256, 0, stream>>>(bufB, srcs, offs, deg, dinv,
                                                            b2, bufA, n);
    fc_head<<<(n + 255) / 256, 256, 0, stream>>>(bufA, fcW1, fcb1, fcW2, fcb2, out, n);
}

// Round 7
// 217.475 us; speedup vs baseline: 2.9990x; 1.1002x over previous
//
#include <hip/hip_runtime.h>

// ---------------------------------------------------------------------------
// GCN pipeline, round 7:
//   histA -> scanTiles -> scanBase -> multisplit2 (deterministic counting
//   sort) -> place_fine2 (per-node CSR + deg/offs/dinv/y) -> agg_xin (5-dim
//   L2-resident aggregate) -> transform12 (FUSED: relu(z@W1+b1) in LDS ->
//   dinv*out1@W2) -> agg2_fc (FUSED: aggregate<32> + relu + FC head).
// Round-6 lesson: aggregate<32>'s 84.6MB fetch is near the structural floor
// (every XCD reads all of h2': ~102MB L2-fill). Remaining time is spread
// across 9 small kernels -> cut dispatches and intermediate HBM round-trips:
// out1 (51MB r+w) and out2 (25.6MB r+w) now never touch global memory.
// ---------------------------------------------------------------------------

#define MS_TILE 2048
#define MAXB 512  // padded coarse-bucket count (NBkt = ceil(n/256) <= 512)

// per-tile LDS histogram of dst>>8 -> histG[tile*512 + b] (coalesced rows)
__global__ __launch_bounds__(256) void histA(const int* __restrict__ dst,
                                             int* __restrict__ histG, int E) {
    __shared__ int h[MAXB];
    int t = threadIdx.x;
    h[t] = 0;
    h[t + 256] = 0;
    __syncthreads();
    int base = blockIdx.x * MS_TILE;
    int cnt = min(MS_TILE, E - base);
    for (int k = t; k < cnt; k += 256) atomicAdd(&h[dst[base + k] >> 8], 1);
    __syncthreads();
    histG[blockIdx.x * MAXB + t] = h[t];
    histG[blockIdx.x * MAXB + 256 + t] = h[t + 256];
}

// one block per bucket b: exclusive scan of histG[.][b] across tiles ->
// offsG[tile*512+b]; bucket total -> bucketTotal[b]
__global__ __launch_bounds__(256) void scanTiles(const int* __restrict__ histG,
                                                 int* __restrict__ offsG,
                                                 int* __restrict__ bucketTotal,
                                                 int nTiles) {
    __shared__ int scn[256];
    int b = blockIdx.x, t = threadIdx.x;
    int run = 0;
    for (int base = 0; base < nTiles; base += 256) {
        int idx = base + t;
        int v = (idx < nTiles) ? histG[idx * MAXB + b] : 0;
        scn[t] = v;
        __syncthreads();
        int incl = v;
        for (int d = 1; d < 256; d <<= 1) {
            int add = (t >= d) ? scn[t - d] : 0;
            __syncthreads();
            incl += add;
            scn[t] = incl;
            __syncthreads();
        }
        if (idx < nTiles) offsG[idx * MAXB + b] = incl - v + run;
        run += scn[255];
        __syncthreads();
    }
    if (t == 0) bucketTotal[b] = run;
}

// single-block exclusive scan of 512 bucket totals -> gbase[0..512]
__global__ __launch_bounds__(256) void scanBase(const int* __restrict__ bucketTotal,
                                                int* __restrict__ gbase, int E) {
    __shared__ int scn[256];
    int t = threadIdx.x;
    int a0 = bucketTotal[2 * t], a1 = bucketTotal[2 * t + 1];
    int s = a0 + a1;
    scn[t] = s;
    __syncthreads();
    int incl = s;
    for (int d = 1; d < 256; d <<= 1) {
        int add = (t >= d) ? scn[t - d] : 0;
        __syncthreads();
        incl += add;
        scn[t] = incl;
        __syncthreads();
    }
    int ex = incl - s;
    gbase[2 * t] = ex;
    gbase[2 * t + 1] = ex + a0;
    if (t == 255) gbase[MAXB] = E;
}

// Deterministic tile counting-sort. Payload: (src<<8)|(dst&255).
__global__ __launch_bounds__(256) void multisplit2(
    const int* __restrict__ src, const int* __restrict__ dst,
    const int* __restrict__ histG, const int* __restrict__ offsG,
    const int* __restrict__ gbase, unsigned* __restrict__ binned, int E) {
    __shared__ unsigned stage[MS_TILE];
    __shared__ unsigned short sb[MS_TILE];
    __shared__ int hoff[MAXB + 1];
    __shared__ int hcur[MAXB];
    __shared__ int gb[MAXB];
    __shared__ int scn[256];
    int t = threadIdx.x;
    int tile = blockIdx.x;
    int base = tile * MS_TILE;
    int cnt = min(MS_TILE, E - base);

    int a0 = histG[tile * MAXB + 2 * t];
    int a1 = histG[tile * MAXB + 2 * t + 1];
    gb[2 * t] = gbase[2 * t] + offsG[tile * MAXB + 2 * t];
    gb[2 * t + 1] = gbase[2 * t + 1] + offsG[tile * MAXB + 2 * t + 1];
    int s = a0 + a1;
    scn[t] = s;
    __syncthreads();
    int incl = s;
    for (int d = 1; d < 256; d <<= 1) {
        int add = (t >= d) ? scn[t - d] : 0;
        __syncthreads();
        incl += add;
        scn[t] = incl;
        __syncthreads();
    }
    int ex = incl - s;
    hoff[2 * t] = ex;
    hoff[2 * t + 1] = ex + a0;
    hcur[2 * t] = ex;
    hcur[2 * t + 1] = ex + a0;
    if (t == 255) hoff[MAXB] = cnt;
    __syncthreads();
    for (int k = t; k < cnt; k += 256) {
        int d = dst[base + k];
        int b = d >> 8;
        int p = atomicAdd(&hcur[b], 1);
        stage[p] = ((unsigned)src[base + k] << 8) | (unsigned)(d & 255);
        sb[p] = (unsigned short)b;
    }
    __syncthreads();
    for (int k = t; k < cnt; k += 256) {
        int b = sb[k];
        binned[gb[b] + (k - hoff[b])] = stage[k];
    }
}

// Per coarse bucket: per-node deg via LDS count, LDS scan -> offs, dinv,
// y[i,:] = dinv[i]*x[i,:] (padded to 8 floats), then exact CSR scatter.
__global__ __launch_bounds__(256) void place_fine2(
    const unsigned* __restrict__ binned, const int* __restrict__ gbase,
    const float* __restrict__ x, int* __restrict__ offs, int* __restrict__ deg,
    float* __restrict__ dinv, float* __restrict__ y, int* __restrict__ srcs, int n) {
    __shared__ int cnt[256];
    __shared__ int scn[256];
    __shared__ int lcur[256];
    int t = threadIdx.x, b = blockIdx.x;
    int node0 = b << 8;
    int nn = min(256, n - node0);
    int e0 = gbase[b], e1 = gbase[b + 1];
    cnt[t] = 0;
    __syncthreads();
    for (int k = e0 + t; k < e1; k += 256) atomicAdd(&cnt[binned[k] & 255u], 1);
    __syncthreads();
    int c = cnt[t];
    scn[t] = c;
    __syncthreads();
    int incl = c;
    for (int d = 1; d < 256; d <<= 1) {
        int add = (t >= d) ? scn[t - d] : 0;
        __syncthreads();
        incl += add;
        scn[t] = incl;
        __syncthreads();
    }
    int myoff = e0 + (incl - c);
    lcur[t] = myoff;
    if (t < nn) {
        int node = node0 + t;
        offs[node] = myoff;
        deg[node] = c;
        float di = 1.0f / sqrtf((float)(c + 1));  // +1 self loop
        dinv[node] = di;
        const float* xr = x + (size_t)node * 5;
        float4 a = {xr[0] * di, xr[1] * di, xr[2] * di, xr[3] * di};
        float4 bq = {xr[4] * di, 0.f, 0.f, 0.f};
        *(float4*)(y + (size_t)node * 8) = a;
        *(float4*)(y + (size_t)node * 8 + 4) = bq;
    }
    __syncthreads();
    for (int k = e0 + t; k < e1; k += 256) {
        unsigned w = binned[k];
        int p = atomicAdd(&lcur[w & 255u], 1);
        srcs[p] = (int)(w >> 8);
    }
}

// z[i,:] = dinv[i]*(y[i,:] + sum_{e:dst=i} y[src,:])  (8-float padded rows,
// 3.2MB working set -> L2-resident random gathers)
__global__ void agg_xin(const float* __restrict__ y, const int* __restrict__ srcs,
                        const int* __restrict__ offs, const int* __restrict__ deg,
                        const float* __restrict__ dinv, float* __restrict__ z, int n) {
    int i = blockIdx.x * blockDim.x + threadIdx.x;
    if (i >= n) return;
    const float4* yv = (const float4*)y;
    float4 a = yv[(size_t)i * 2];
    float4 b = yv[(size_t)i * 2 + 1];
    int off = offs[i], cnt = deg[i];
    int p = 0;
    for (; p + 2 <= cnt; p += 2) {
        int s0 = srcs[off + p], s1 = srcs[off + p + 1];
        float4 v0 = yv[(size_t)s0 * 2];
        float4 w0 = yv[(size_t)s0 * 2 + 1];
        float4 v1 = yv[(size_t)s1 * 2];
        float4 w1 = yv[(size_t)s1 * 2 + 1];
        a.x += v0.x + v1.x; a.y += v0.y + v1.y; a.z += v0.z + v1.z; a.w += v0.w + v1.w;
        b.x += w0.x + w1.x;
    }
    if (p < cnt) {
        int s0 = srcs[off + p];
        float4 v0 = yv[(size_t)s0 * 2];
        float w0 = y[(size_t)s0 * 8 + 4];
        a.x += v0.x; a.y += v0.y; a.z += v0.z; a.w += v0.w;
        b.x += w0;
    }
    float di = dinv[i];
    float4 oa = {a.x * di, a.y * di, a.z * di, a.w * di};
    float4 ob = {b.x * di, 0.f, 0.f, 0.f};
    float4* zv = (float4*)z;
    zv[(size_t)i * 2] = oa;
    zv[(size_t)i * 2 + 1] = ob;
}

// FUSED transforms: out1 = relu(z@W1 + b1) kept in LDS; h2' = dinv*(out1@W2).
// Block = 32 nodes. LDS: W1 320 + b1 64 + W2 2048 + out1 2048 floats (~17.9KB).
__global__ __launch_bounds__(256) void transform12(
    const float* __restrict__ z, const float* __restrict__ W1,
    const float* __restrict__ b1, const float* __restrict__ W2,
    const float* __restrict__ dinv, float* __restrict__ h2, int n) {
    __shared__ float w1s[320];
    __shared__ float b1s[64];
    __shared__ float w2s[64 * 32];
    __shared__ float o1[32 * 64];
    int t = threadIdx.x;
    w1s[t] = W1[t];
    if (t < 64) {
        w1s[t + 256] = W1[t + 256];
        b1s[t] = b1[t];
    }
#pragma unroll
    for (int r = 0; r < 8; ++r) w2s[r * 256 + t] = W2[r * 256 + t];
    __syncthreads();
    int node0 = blockIdx.x * 32;
    // phase A: out1 rows into LDS (32 nodes x 64 feats)
#pragma unroll
    for (int r = 0; r < 8; ++r) {
        int idx = r * 256 + t;
        int li = idx >> 6, f = idx & 63;
        int i = node0 + li;
        if (i < n) {
            const float* zr = z + (size_t)i * 8;
            float acc = b1s[f];
#pragma unroll
            for (int k = 0; k < 5; ++k) acc += zr[k] * w1s[k * 64 + f];
            o1[li * 64 + f] = fmaxf(acc, 0.0f);
        }
    }
    __syncthreads();
    // phase B: h2'[i,g] = dinv[i] * sum_k o1[li,k]*W2[k,g]
#pragma unroll
    for (int r = 0; r < 4; ++r) {
        int idx = r * 256 + t;
        int li = idx >> 5, g = idx & 31;
        int i = node0 + li;
        if (i < n) {
            float acc = 0.f;
#pragma unroll
            for (int k = 0; k < 64; ++k) acc += o1[li * 64 + k] * w2s[k * 32 + g];
            h2[(size_t)i * 32 + g] = acc * dinv[i];
        }
    }
}

// FUSED layer-2 aggregate + FC head. Block = 8 nodes x 32 feats.
// out2 = relu(dinv*(h'[i]+sum h'[src]) + b2) staged in LDS (never to global);
// x3 = relu(out2@fcW1+fcb1); out = x3@fcW2+fcb2.
__global__ __launch_bounds__(256) void agg2_fc(
    const float* __restrict__ h, const int* __restrict__ srcs,
    const int* __restrict__ offs, const int* __restrict__ deg,
    const float* __restrict__ dinv, const float* __restrict__ b2,
    const float* __restrict__ fcW1, const float* __restrict__ fcb1,
    const float* __restrict__ fcW2, const float* __restrict__ fcb2,
    float* __restrict__ out, int n) {
    __shared__ float sm[256];       // out2 chunk: 8 nodes x 32
    __shared__ float x3s[8 * 16];   // hidden: 8 nodes x 16
    __shared__ float w1s[512];
    __shared__ float w2s[32];
    __shared__ float b1s[16];
    __shared__ float b2s[2];
    __shared__ float bs2[32];
    int t = threadIdx.x;
    w1s[t] = fcW1[t];
    w1s[t + 256] = fcW1[t + 256];
    if (t < 32) { w2s[t] = fcW2[t]; bs2[t] = b2[t]; }
    if (t < 16) b1s[t] = fcb1[t];
    if (t < 2) b2s[t] = fcb2[t];

    int idx = blockIdx.x * 256 + t;
    int i = idx >> 5, f = idx & 31;
    bool live = (i < n);
    float acc = 0.f;
    int off = 0, cnt = 0;
    if (live) {
        acc = h[(size_t)i * 32 + f];  // self-loop term (pre-scaled)
        off = offs[i];
        cnt = deg[i];
    }
    int p = 0;
    for (; p + 8 <= cnt; p += 8) {
        int s[8];
#pragma unroll
        for (int u = 0; u < 8; ++u) s[u] = srcs[off + p + u];
        float v[8];
#pragma unroll
        for (int u = 0; u < 8; ++u) v[u] = h[(size_t)s[u] * 32 + f];
#pragma unroll
        for (int u = 0; u < 8; ++u) acc += v[u];
    }
    for (; p < cnt; ++p) acc += h[(size_t)srcs[off + p] * 32 + f];
    __syncthreads();  // weight loads done; also orders sm reuse
    if (live) {
        float v = dinv[i] * acc + bs2[f];
        sm[t] = fmaxf(v, 0.0f);
    }
    __syncthreads();
    int node0 = blockIdx.x * 8;
    if (t < 128) {
        int li = t >> 4, j = t & 15;
        if (node0 + li < n) {
            float a = b1s[j];
#pragma unroll
            for (int k = 0; k < 32; ++k) a += sm[li * 32 + k] * w1s[k * 16 + j];
            x3s[li * 16 + j] = fmaxf(a, 0.f);
        }
    }
    __syncthreads();
    if (t < 16) {
        int li = t >> 1, o = t & 1;
        if (node0 + li < n) {
            float a = b2s[o];
#pragma unroll
            for (int j = 0; j < 16; ++j) a += x3s[li * 16 + j] * w2s[j * 2 + o];
            out[(size_t)(node0 + li) * 2 + o] = a;
        }
    }
}

extern "C" void kernel_launch(void* const* d_in, const int* in_sizes, int n_in,
                              void* d_out, int out_size, void* d_ws, size_t ws_size,
                              hipStream_t stream) {
    const float* edge_attr = (const float*)d_in[0];
    const int* edge_index  = (const int*)d_in[1];
    const float* W1   = (const float*)d_in[2];
    const float* b1   = (const float*)d_in[3];
    const float* W2   = (const float*)d_in[4];
    const float* b2   = (const float*)d_in[5];
    const float* fcW1 = (const float*)d_in[6];
    const float* fcb1 = (const float*)d_in[7];
    const float* fcW2 = (const float*)d_in[8];
    const float* fcb2 = (const float*)d_in[9];
    float* out = (float*)d_out;

    int n = in_sizes[0] / 5;
    int E = in_sizes[1] / 2;
    int NBkt = (n + 255) >> 8;                 // 391 for n=100000 (<= MAXB)
    int nTiles = (E + MS_TILE - 1) / MS_TILE;  // 782
    const int* src = edge_index;
    const int* dst = edge_index + E;

    char* ws = (char*)d_ws;
    auto alloc = [&](size_t bytes) {
        char* p = ws;
        ws += (bytes + 255) & ~(size_t)255;
        return p;
    };
    int*      deg    = (int*)alloc((size_t)n * 4);
    int*      offs   = (int*)alloc((size_t)n * 4);
    float*    dinv   = (float*)alloc((size_t)n * 4);
    int*      histG  = (int*)alloc((size_t)nTiles * MAXB * 4);
    int*      offsG  = (int*)alloc((size_t)nTiles * MAXB * 4);
    int*      btot   = (int*)alloc((size_t)MAXB * 4);
    int*      gbase  = (int*)alloc((size_t)(MAXB + 1) * 4);
    int*      srcs   = (int*)alloc((size_t)E * 4);
    unsigned* binned = (unsigned*)alloc((size_t)E * 4);
    float*    y      = (float*)alloc((size_t)n * 8 * 4);
    float*    z      = (float*)alloc((size_t)n * 8 * 4);
    float*    h2     = (float*)alloc((size_t)n * 32 * 4);

    histA<<<nTiles, 256, 0, stream>>>(dst, histG, E);
    scanTiles<<<MAXB, 256, 0, stream>>>(histG, offsG, btot, nTiles);
    scanBase<<<1, 256, 0, stream>>>(btot, gbase, E);
    multisplit2<<<nTiles, 256, 0, stream>>>(src, dst, histG, offsG, gbase, binned, E);
    place_fine2<<<NBkt, 256, 0, stream>>>(binned, gbase, edge_attr, offs, deg, dinv,
                                          y, srcs, n);

    agg_xin<<<(n + 255) / 256, 256, 0, stream>>>(y, srcs, offs, deg, dinv, z, n);
    transform12<<<(n + 31) / 32, 256, 0, stream>>>(z, W1, b1, W2, dinv, h2, n);
    agg2_fc<<<(n * 32 + 255) / 256, 256, 0, stream>>>(h2, srcs, offs, deg, dinv, b2,
                                                      fcW1, fcb1, fcW2, fcb2, out, n);
}

// Round 8
// 200.042 us; speedup vs baseline: 3.2604x; 1.0871x over previous
//
#include <hip/hip_runtime.h>

// ---------------------------------------------------------------------------
// GCN pipeline, round 8:
//   histA -> scanTiles -> scanBase -> multisplit2 -> place_fine2 ->
//   agg_xin -> transform12 (fused transforms) -> agg2_fc v2 (32 nodes/block,
//   LDS-staged CSR indices, float4 gathers, LDS out2 -> FC head).
// Round-7 lesson: agg2_fc was issue-bound (VALUBusy 25%, 1.6 TB/s fetch,
// 4x off the BW floor): 32 feat-threads per node each re-loaded the same
// srcs[] stream and gathered 4B at a time. v2 stages the block's contiguous
// CSR segment in LDS once (coalesced, pre-scaled to byte offsets) and
// gathers float4 per thread -> ~3x fewer VMEM+VALU ops per edge.
// ---------------------------------------------------------------------------

#define MS_TILE 2048
#define MAXB 512  // padded coarse-bucket count (NBkt = ceil(n/256) <= 512)
#define AGG_NODES 32
#define AGG_STAGE 1024

// per-tile LDS histogram of dst>>8 -> histG[tile*512 + b] (coalesced rows)
__global__ __launch_bounds__(256) void histA(const int* __restrict__ dst,
                                             int* __restrict__ histG, int E) {
    __shared__ int h[MAXB];
    int t = threadIdx.x;
    h[t] = 0;
    h[t + 256] = 0;
    __syncthreads();
    int base = blockIdx.x * MS_TILE;
    int cnt = min(MS_TILE, E - base);
    for (int k = t; k < cnt; k += 256) atomicAdd(&h[dst[base + k] >> 8], 1);
    __syncthreads();
    histG[blockIdx.x * MAXB + t] = h[t];
    histG[blockIdx.x * MAXB + 256 + t] = h[t + 256];
}

// one block per bucket b: exclusive scan of histG[.][b] across tiles ->
// offsG[tile*512+b]; bucket total -> bucketTotal[b]
__global__ __launch_bounds__(256) void scanTiles(const int* __restrict__ histG,
                                                 int* __restrict__ offsG,
                                                 int* __restrict__ bucketTotal,
                                                 int nTiles) {
    __shared__ int scn[256];
    int b = blockIdx.x, t = threadIdx.x;
    int run = 0;
    for (int base = 0; base < nTiles; base += 256) {
        int idx = base + t;
        int v = (idx < nTiles) ? histG[idx * MAXB + b] : 0;
        scn[t] = v;
        __syncthreads();
        int incl = v;
        for (int d = 1; d < 256; d <<= 1) {
            int add = (t >= d) ? scn[t - d] : 0;
            __syncthreads();
            incl += add;
            scn[t] = incl;
            __syncthreads();
        }
        if (idx < nTiles) offsG[idx * MAXB + b] = incl - v + run;
        run += scn[255];
        __syncthreads();
    }
    if (t == 0) bucketTotal[b] = run;
}

// single-block exclusive scan of 512 bucket totals -> gbase[0..512]
__global__ __launch_bounds__(256) void scanBase(const int* __restrict__ bucketTotal,
                                                int* __restrict__ gbase, int E) {
    __shared__ int scn[256];
    int t = threadIdx.x;
    int a0 = bucketTotal[2 * t], a1 = bucketTotal[2 * t + 1];
    int s = a0 + a1;
    scn[t] = s;
    __syncthreads();
    int incl = s;
    for (int d = 1; d < 256; d <<= 1) {
        int add = (t >= d) ? scn[t - d] : 0;
        __syncthreads();
        incl += add;
        scn[t] = incl;
        __syncthreads();
    }
    int ex = incl - s;
    gbase[2 * t] = ex;
    gbase[2 * t + 1] = ex + a0;
    if (t == 255) gbase[MAXB] = E;
}

// Deterministic tile counting-sort. Payload: (src<<8)|(dst&255).
__global__ __launch_bounds__(256) void multisplit2(
    const int* __restrict__ src, const int* __restrict__ dst,
    const int* __restrict__ histG, const int* __restrict__ offsG,
    const int* __restrict__ gbase, unsigned* __restrict__ binned, int E) {
    __shared__ unsigned stage[MS_TILE];
    __shared__ unsigned short sb[MS_TILE];
    __shared__ int hoff[MAXB + 1];
    __shared__ int hcur[MAXB];
    __shared__ int gb[MAXB];
    __shared__ int scn[256];
    int t = threadIdx.x;
    int tile = blockIdx.x;
    int base = tile * MS_TILE;
    int cnt = min(MS_TILE, E - base);

    int a0 = histG[tile * MAXB + 2 * t];
    int a1 = histG[tile * MAXB + 2 * t + 1];
    gb[2 * t] = gbase[2 * t] + offsG[tile * MAXB + 2 * t];
    gb[2 * t + 1] = gbase[2 * t + 1] + offsG[tile * MAXB + 2 * t + 1];
    int s = a0 + a1;
    scn[t] = s;
    __syncthreads();
    int incl = s;
    for (int d = 1; d < 256; d <<= 1) {
        int add = (t >= d) ? scn[t - d] : 0;
        __syncthreads();
        incl += add;
        scn[t] = incl;
        __syncthreads();
    }
    int ex = incl - s;
    hoff[2 * t] = ex;
    hoff[2 * t + 1] = ex + a0;
    hcur[2 * t] = ex;
    hcur[2 * t + 1] = ex + a0;
    if (t == 255) hoff[MAXB] = cnt;
    __syncthreads();
    for (int k = t; k < cnt; k += 256) {
        int d = dst[base + k];
        int b = d >> 8;
        int p = atomicAdd(&hcur[b], 1);
        stage[p] = ((unsigned)src[base + k] << 8) | (unsigned)(d & 255);
        sb[p] = (unsigned short)b;
    }
    __syncthreads();
    for (int k = t; k < cnt; k += 256) {
        int b = sb[k];
        binned[gb[b] + (k - hoff[b])] = stage[k];
    }
}

// Per coarse bucket: per-node deg via LDS count, LDS scan -> offs, dinv,
// y[i,:] = dinv[i]*x[i,:] (padded to 8 floats), then exact CSR scatter.
__global__ __launch_bounds__(256) void place_fine2(
    const unsigned* __restrict__ binned, const int* __restrict__ gbase,
    const float* __restrict__ x, int* __restrict__ offs, int* __restrict__ deg,
    float* __restrict__ dinv, float* __restrict__ y, int* __restrict__ srcs, int n) {
    __shared__ int cnt[256];
    __shared__ int scn[256];
    __shared__ int lcur[256];
    int t = threadIdx.x, b = blockIdx.x;
    int node0 = b << 8;
    int nn = min(256, n - node0);
    int e0 = gbase[b], e1 = gbase[b + 1];
    cnt[t] = 0;
    __syncthreads();
    for (int k = e0 + t; k < e1; k += 256) atomicAdd(&cnt[binned[k] & 255u], 1);
    __syncthreads();
    int c = cnt[t];
    scn[t] = c;
    __syncthreads();
    int incl = c;
    for (int d = 1; d < 256; d <<= 1) {
        int add = (t >= d) ? scn[t - d] : 0;
        __syncthreads();
        incl += add;
        scn[t] = incl;
        __syncthreads();
    }
    int myoff = e0 + (incl - c);
    lcur[t] = myoff;
    if (t < nn) {
        int node = node0 + t;
        offs[node] = myoff;
        deg[node] = c;
        float di = 1.0f / sqrtf((float)(c + 1));  // +1 self loop
        dinv[node] = di;
        const float* xr = x + (size_t)node * 5;
        float4 a = {xr[0] * di, xr[1] * di, xr[2] * di, xr[3] * di};
        float4 bq = {xr[4] * di, 0.f, 0.f, 0.f};
        *(float4*)(y + (size_t)node * 8) = a;
        *(float4*)(y + (size_t)node * 8 + 4) = bq;
    }
    __syncthreads();
    for (int k = e0 + t; k < e1; k += 256) {
        unsigned w = binned[k];
        int p = atomicAdd(&lcur[w & 255u], 1);
        srcs[p] = (int)(w >> 8);
    }
}

// z[i,:] = dinv[i]*(y[i,:] + sum_{e:dst=i} y[src,:])  (8-float padded rows,
// 3.2MB working set -> L2-resident random gathers)
__global__ void agg_xin(const float* __restrict__ y, const int* __restrict__ srcs,
                        const int* __restrict__ offs, const int* __restrict__ deg,
                        const float* __restrict__ dinv, float* __restrict__ z, int n) {
    int i = blockIdx.x * blockDim.x + threadIdx.x;
    if (i >= n) return;
    const float4* yv = (const float4*)y;
    float4 a = yv[(size_t)i * 2];
    float4 b = yv[(size_t)i * 2 + 1];
    int off = offs[i], cnt = deg[i];
    int p = 0;
    for (; p + 2 <= cnt; p += 2) {
        int s0 = srcs[off + p], s1 = srcs[off + p + 1];
        float4 v0 = yv[(size_t)s0 * 2];
        float4 w0 = yv[(size_t)s0 * 2 + 1];
        float4 v1 = yv[(size_t)s1 * 2];
        float4 w1 = yv[(size_t)s1 * 2 + 1];
        a.x += v0.x + v1.x; a.y += v0.y + v1.y; a.z += v0.z + v1.z; a.w += v0.w + v1.w;
        b.x += w0.x + w1.x;
    }
    if (p < cnt) {
        int s0 = srcs[off + p];
        float4 v0 = yv[(size_t)s0 * 2];
        float w0 = y[(size_t)s0 * 8 + 4];
        a.x += v0.x; a.y += v0.y; a.z += v0.z; a.w += v0.w;
        b.x += w0;
    }
    float di = dinv[i];
    float4 oa = {a.x * di, a.y * di, a.z * di, a.w * di};
    float4 ob = {b.x * di, 0.f, 0.f, 0.f};
    float4* zv = (float4*)z;
    zv[(size_t)i * 2] = oa;
    zv[(size_t)i * 2 + 1] = ob;
}

// FUSED transforms: out1 = relu(z@W1 + b1) kept in LDS; h2' = dinv*(out1@W2).
__global__ __launch_bounds__(256) void transform12(
    const float* __restrict__ z, const float* __restrict__ W1,
    const float* __restrict__ b1, const float* __restrict__ W2,
    const float* __restrict__ dinv, float* __restrict__ h2, int n) {
    __shared__ float w1s[320];
    __shared__ float b1s[64];
    __shared__ float w2s[64 * 32];
    __shared__ float o1[32 * 64];
    int t = threadIdx.x;
    w1s[t] = W1[t];
    if (t < 64) {
        w1s[t + 256] = W1[t + 256];
        b1s[t] = b1[t];
    }
#pragma unroll
    for (int r = 0; r < 8; ++r) w2s[r * 256 + t] = W2[r * 256 + t];
    __syncthreads();
    int node0 = blockIdx.x * 32;
#pragma unroll
    for (int r = 0; r < 8; ++r) {
        int idx = r * 256 + t;
        int li = idx >> 6, f = idx & 63;
        int i = node0 + li;
        if (i < n) {
            const float* zr = z + (size_t)i * 8;
            float acc = b1s[f];
#pragma unroll
            for (int k = 0; k < 5; ++k) acc += zr[k] * w1s[k * 64 + f];
            o1[li * 64 + f] = fmaxf(acc, 0.0f);
        }
    }
    __syncthreads();
#pragma unroll
    for (int r = 0; r < 4; ++r) {
        int idx = r * 256 + t;
        int li = idx >> 5, g = idx & 31;
        int i = node0 + li;
        if (i < n) {
            float acc = 0.f;
#pragma unroll
            for (int k = 0; k < 64; ++k) acc += o1[li * 64 + k] * w2s[k * 32 + g];
            h2[(size_t)i * 32 + g] = acc * dinv[i];
        }
    }
}

// FUSED layer-2 aggregate + FC head, v2.
// Block = 32 nodes x 8 f4-groups. The block's CSR segment [offs[node0],
// offs[node0+32]) is contiguous -> staged into LDS once (coalesced), entries
// pre-scaled to row byte offsets. Each thread gathers float4 rows.
__global__ __launch_bounds__(256) void agg2_fc(
    const float* __restrict__ h, const int* __restrict__ srcs,
    const int* __restrict__ offs, const int* __restrict__ deg,
    const float* __restrict__ dinv, const float* __restrict__ b2,
    const float* __restrict__ fcW1, const float* __restrict__ fcb1,
    const float* __restrict__ fcW2, const float* __restrict__ fcb2,
    float* __restrict__ out, int n, int E) {
    __shared__ int sidx[AGG_STAGE];
    __shared__ float sm[AGG_NODES * 33];  // out2, stride-33 padded
    __shared__ float x3s[AGG_NODES * 16];
    __shared__ float w1s[512];
    __shared__ float w2s[32];
    __shared__ float b1s[16];
    __shared__ float b2s[2];
    __shared__ float bs2[32];
    int t = threadIdx.x;
    w1s[t] = fcW1[t];
    w1s[t + 256] = fcW1[t + 256];
    if (t < 32) { w2s[t] = fcW2[t]; bs2[t] = b2[t]; }
    if (t < 16) b1s[t] = fcb1[t];
    if (t < 2) b2s[t] = fcb2[t];

    int node0 = blockIdx.x * AGG_NODES;
    int li = t >> 3, fq = t & 7;  // node-in-block, 4-feature group
    int i = node0 + li;
    bool live = (i < n);
    const char* hb = (const char*)h;

    int e0 = offs[node0];
    int eEnd = (node0 + AGG_NODES < n) ? offs[node0 + AGG_NODES] : E;
    int myOff = 0, myCnt = 0;
    float4 acc = {0.f, 0.f, 0.f, 0.f};
    if (live) {
        myOff = offs[i];
        myCnt = deg[i];
        acc = *(const float4*)(hb + ((size_t)i << 7) + (fq << 4));  // self-loop
    }

    for (int cs = e0; cs < eEnd; cs += AGG_STAGE) {
        int ce = min(cs + AGG_STAGE, eEnd);
        for (int k = cs + t; k < ce; k += 256) sidx[k - cs] = srcs[k] << 7;
        __syncthreads();
        int ps = max(myOff, cs), pe = min(myOff + myCnt, ce);
        int p = ps;
        for (; p + 4 <= pe; p += 4) {
            int o0 = sidx[p - cs];
            int o1 = sidx[p + 1 - cs];
            int o2 = sidx[p + 2 - cs];
            int o3 = sidx[p + 3 - cs];
            float4 v0 = *(const float4*)(hb + o0 + (fq << 4));
            float4 v1 = *(const float4*)(hb + o1 + (fq << 4));
            float4 v2 = *(const float4*)(hb + o2 + (fq << 4));
            float4 v3 = *(const float4*)(hb + o3 + (fq << 4));
            acc.x += (v0.x + v1.x) + (v2.x + v3.x);
            acc.y += (v0.y + v1.y) + (v2.y + v3.y);
            acc.z += (v0.z + v1.z) + (v2.z + v3.z);
            acc.w += (v0.w + v1.w) + (v2.w + v3.w);
        }
        for (; p < pe; ++p) {
            float4 v = *(const float4*)(hb + sidx[p - cs] + (fq << 4));
            acc.x += v.x; acc.y += v.y; acc.z += v.z; acc.w += v.w;
        }
        __syncthreads();
    }

    if (live) {
        float di = dinv[i];
        int f0 = fq << 2;
        sm[li * 33 + f0 + 0] = fmaxf(di * acc.x + bs2[f0 + 0], 0.f);
        sm[li * 33 + f0 + 1] = fmaxf(di * acc.y + bs2[f0 + 1], 0.f);
        sm[li * 33 + f0 + 2] = fmaxf(di * acc.z + bs2[f0 + 2], 0.f);
        sm[li * 33 + f0 + 3] = fmaxf(di * acc.w + bs2[f0 + 3], 0.f);
    }
    __syncthreads();
    // fc1: 32 nodes x 16 hidden = 512 items over 256 threads x 2
#pragma unroll
    for (int r = 0; r < 2; ++r) {
        int idx = r * 256 + t;
        int lj = idx >> 4, j = idx & 15;
        if (node0 + lj < n) {
            float a = b1s[j];
#pragma unroll
            for (int k = 0; k < 32; ++k) a += sm[lj * 33 + k] * w1s[k * 16 + j];
            x3s[lj * 16 + j] = fmaxf(a, 0.f);
        }
    }
    __syncthreads();
    // fc2: 32 nodes x 2 outputs = 64 items (coalesced 256B store)
    if (t < 64) {
        int lj = t >> 1, o = t & 1;
        if (node0 + lj < n) {
            float a = b2s[o];
#pragma unroll
            for (int j = 0; j < 16; ++j) a += x3s[lj * 16 + j] * w2s[j * 2 + o];
            out[(size_t)(node0 + lj) * 2 + o] = a;
        }
    }
}

extern "C" void kernel_launch(void* const* d_in, const int* in_sizes, int n_in,
                              void* d_out, int out_size, void* d_ws, size_t ws_size,
                              hipStream_t stream) {
    const float* edge_attr = (const float*)d_in[0];
    const int* edge_index  = (const int*)d_in[1];
    const float* W1   = (const float*)d_in[2];
    const float* b1   = (const float*)d_in[3];
    const float* W2   = (const float*)d_in[4];
    const float* b2   = (const float*)d_in[5];
    const float* fcW1 = (const float*)d_in[6];
    const float* fcb1 = (const float*)d_in[7];
    const float* fcW2 = (const float*)d_in[8];
    const float* fcb2 = (const float*)d_in[9];
    float* out = (float*)d_out;

    int n = in_sizes[0] / 5;
    int E = in_sizes[1] / 2;
    int NBkt = (n + 255) >> 8;                 // 391 for n=100000 (<= MAXB)
    int nTiles = (E + MS_TILE - 1) / MS_TILE;  // 782
    const int* src = edge_index;
    const int* dst = edge_index + E;

    char* ws = (char*)d_ws;
    auto alloc = [&](size_t bytes) {
        char* p = ws;
        ws += (bytes + 255) & ~(size_t)255;
        return p;
    };
    int*      deg    = (int*)alloc((size_t)n * 4);
    int*      offs   = (int*)alloc((size_t)n * 4);
    float*    dinv   = (float*)alloc((size_t)n * 4);
    int*      histG  = (int*)alloc((size_t)nTiles * MAXB * 4);
    int*      offsG  = (int*)alloc((size_t)nTiles * MAXB * 4);
    int*      btot   = (int*)alloc((size_t)MAXB * 4);
    int*      gbase  = (int*)alloc((size_t)(MAXB + 1) * 4);
    int*      srcs   = (int*)alloc((size_t)E * 4);
    unsigned* binned = (unsigned*)alloc((size_t)E * 4);
    float*    y      = (float*)alloc((size_t)n * 8 * 4);
    float*    z      = (float*)alloc((size_t)n * 8 * 4);
    float*    h2     = (float*)alloc((size_t)n * 32 * 4);

    histA<<<nTiles, 256, 0, stream>>>(dst, histG, E);
    scanTiles<<<MAXB, 256, 0, stream>>>(histG, offsG, btot, nTiles);
    scanBase<<<1, 256, 0, stream>>>(btot, gbase, E);
    multisplit2<<<nTiles, 256, 0, stream>>>(src, dst, histG, offsG, gbase, binned, E);
    place_fine2<<<NBkt, 256, 0, stream>>>(binned, gbase, edge_attr, offs, deg, dinv,
                                          y, srcs, n);

    agg_xin<<<(n + 255) / 256, 256, 0, stream>>>(y, srcs, offs, deg, dinv, z, n);
    transform12<<<(n + 31) / 32, 256, 0, stream>>>(z, W1, b1, W2, dinv, h2, n);
    agg2_fc<<<(n + AGG_NODES - 1) / AGG_NODES, 256, 0, stream>>>(
        h2, srcs, offs, deg, dinv, b2, fcW1, fcb1, fcW2, fcb2, out, n, E);
}